// Round 10
// baseline (3214.494 us; speedup 1.0000x reference)
//
#include <hip/hip_runtime.h>
#include <math.h>

#define NNODES 32768
#define NEDGES 524288
#define KDIM 32
#define NSHD 16
#define NB 8
#define NHID 64
#define NGRAPH 16
#define NELEM 10
#define RMAXF 5.0f
#define INVR_MAX 0.2f
#define PI_F 3.14159265358979f
#define CBES 0.632455532033676f   /* sqrt(2/R_MAX) */
#define LUTN 2048
#define NPAIR 136                 /* 16*17/2 symmetric (j<=l) pairs */

// 16 named outputs: keeps SH values in VGPRs (array form triggered
// PromoteAlloca -> LDS with 32-way bank conflicts, R5 post-mortem).
__device__ __forceinline__ void compute_sh16(float x, float y, float z,
    float& s0, float& s1, float& s2, float& s3,
    float& s4, float& s5, float& s6, float& s7,
    float& s8, float& s9, float& s10, float& s11,
    float& s12, float& s13, float& s14, float& s15){
  float x2=x*x, y2=y*y, z2=z*z;
  s0=0.28209479f;
  s1=0.48860251f*y;
  s2=0.48860251f*z;
  s3=0.48860251f*x;
  s4=1.09254843f*x*y;
  s5=1.09254843f*y*z;
  s6=0.31539157f*(3.0f*z2-1.0f);
  s7=1.09254843f*x*z;
  s8=0.54627422f*(x2-y2);
  s9=0.59004359f*y*(3.0f*x2-y2);
  s10=2.89061144f*x*y*z;
  s11=0.45704579f*y*(5.0f*z2-1.0f);
  s12=0.37317633f*z*(5.0f*z2-3.0f);
  s13=0.45704579f*x*(5.0f*z2-1.0f);
  s14=1.44530572f*z*(x2-y2);
  s15=0.59004359f*x*(x2-3.0f*y2);
}

// ---------------------------------------------------------------- prep
__global__ void prep_kernel(const float* __restrict__ U2, const float* __restrict__ U3,
                            const float* __restrict__ Wp1, const float* __restrict__ Wp2,
                            const float* __restrict__ Wp3, const float* __restrict__ Wread,
                            float* __restrict__ S3, float* __restrict__ U2s,
                            float* __restrict__ c123){
  int t = threadIdx.x;
  for (int v = t; v < NPAIR*16; v += 256){
    int pid = v >> 4, i = v & 15;
    int j = 0, rem = pid;
    while (rem >= 16 - j){ rem -= 16 - j; j++; }
    int l = j + rem;
    float s;
    if (j == l){
      s = U3[i*256 + j*16 + j] + U3[j*256 + i*16 + j] + U3[j*256 + j*16 + i];
    } else {
      s = U3[i*256 + j*16 + l] + U3[j*256 + i*16 + l] + U3[j*256 + l*16 + i]
        + U3[i*256 + l*16 + j] + U3[l*256 + i*16 + j] + U3[l*256 + j*16 + i];
    }
    S3[v] = s;
  }
  {
    int i = t >> 4, j = t & 15;
    U2s[t] = U2[i*16+j] + U2[j*16+i];
  }
  if (t < 96){
    int which = t >> 5, k = t & 31;
    const float* Wp = (which==0)?Wp1:((which==1)?Wp2:Wp3);
    float s = 0.f;
    for (int q=0;q<KDIM;q++) s += Wp[k*KDIM+q]*Wread[q];
    c123[t] = s;
  }
}

// ---------------------------------------------------------------- radial LUT
__global__ void lut_kernel(const float* __restrict__ W_r1, const float* __restrict__ b_r1,
                           const float* __restrict__ W_r2, float* __restrict__ lut){
  int g = blockIdx.x*256 + threadIdx.x;
  if (g > LUTN) return;
  float r = fmaxf(5.0f*(float)g/(float)LUTN, 1e-9f);
  float invr = 1.0f/r;
  float u = r*INVR_MAX;
  float cut = 0.f, dcdr = 0.f;
  if (u < 1.0f){
    float u2=u*u, u3=u2*u, u6=u3*u3;
    cut = 1.0f - 28.0f*u6 + 48.0f*u6*u - 21.0f*u6*u2;
    float u4=u2*u2, om=1.0f-u;
    dcdr = -168.0f*u4*u*om*om*INVR_MAX;
  }
  float b[NB], db[NB];
  #pragma unroll
  for (int q=0;q<NB;q++){
    float nn = (float)(q+1);
    float ang = PI_F*nn*u;
    float S = sinf(ang), C = cosf(ang);
    b[q]  = CBES*S*invr*cut;
    db[q] = CBES*invr*((PI_F*nn*INVR_MAX)*C - S*invr)*cut + CBES*S*invr*dcdr;
  }
  float Rw[KDIM], dRw[KDIM];
  #pragma unroll
  for (int k=0;k<KDIM;k++){ Rw[k]=0.f; dRw[k]=0.f; }
  for (int m=0;m<NHID;m++){
    float h = b_r1[m], dh = 0.f;
    #pragma unroll
    for (int q=0;q<NB;q++){ h += b[q]*W_r1[q*NHID+m]; dh += db[q]*W_r1[q*NHID+m]; }
    float sg = 1.0f/(1.0f+expf(-h));
    float s  = h*sg;
    float sp = sg*(1.0f + h*(1.0f-sg));
    float f  = sp*dh;
    #pragma unroll
    for (int k=0;k<KDIM;k++){
      Rw[k]  += s*W_r2[m*KDIM+k];
      dRw[k] += f*W_r2[m*KDIM+k];
    }
  }
  #pragma unroll
  for (int k=0;k<KDIM;k++){
    lut[(size_t)g*64 + k]      = Rw[k];
    lut[(size_t)g*64 + 32 + k] = dRw[k];
  }
}

// ---------------------------------------------------------------- CSR build (receiver)
__global__ void csr_count_kernel(const int* __restrict__ eidx, int* __restrict__ cnt){
  int e = blockIdx.x*256 + threadIdx.x;
  if (e < NEDGES) atomicAdd(&cnt[eidx[NEDGES + e]], 1);
}

__global__ void csr_scan_kernel(const int* __restrict__ cnt, int* __restrict__ row_start,
                                int* __restrict__ woff){
  __shared__ int part[1024];
  int t = threadIdx.x;
  int base_idx = t*32;
  int local[32];
  int s = 0;
  #pragma unroll
  for (int j=0;j<32;j++){
    int c = cnt[base_idx+j];
    local[j] = s;
    s += c;
  }
  part[t] = s;
  __syncthreads();
  for (int off=1; off<1024; off<<=1){
    int v = (t>=off) ? part[t-off] : 0;
    __syncthreads();
    part[t] += v;
    __syncthreads();
  }
  int base = (t==0) ? 0 : part[t-1];
  #pragma unroll
  for (int j=0;j<32;j++){
    int v = base + local[j];
    row_start[base_idx+j] = v;
    woff[base_idx+j] = v;
  }
  if (t==1023) row_start[NNODES] = part[1023];
}

__global__ void csr_scatter_kernel(const int* __restrict__ eidx, int* __restrict__ woff,
                                   int* __restrict__ elist){
  int e = blockIdx.x*256 + threadIdx.x;
  if (e < NEDGES){
    int rcv = eidx[NEDGES + e];
    int p = atomicAdd(&woff[rcv], 1);
    elist[p] = e;
  }
}

// ---------------------------------------------------------------- CSR build (sender, over CSR positions)
__global__ void csr2_count_kernel(const int* __restrict__ sndbuf, int* __restrict__ cnt2){
  int p = blockIdx.x*256 + threadIdx.x;
  if (p < NEDGES) atomicAdd(&cnt2[sndbuf[p]], 1);
}

__global__ void csr2_scatter_kernel(const int* __restrict__ sndbuf, int* __restrict__ woff2,
                                    int* __restrict__ elist2){
  int p = blockIdx.x*256 + threadIdx.x;
  if (p < NEDGES){
    int s = sndbuf[p];
    int slot = atomicAdd(&woff2[s], 1);
    elist2[slot] = p;
  }
}

// ---------------------------------------------------------------- node embed
__global__ void node_embed_kernel(const float* __restrict__ attrs,
                                  const float* __restrict__ W_embed,
                                  const float* __restrict__ W_up,
                                  const float* __restrict__ ae,
                                  float* __restrict__ xbuf, float* __restrict__ ybuf,
                                  float* __restrict__ e0con){
  int gtid = blockIdx.x*256 + threadIdx.x;
  int n = gtid >> 6;
  int lane = threadIdx.x & 63;
  int k = lane & 31;
  float xv = 0.f;
  #pragma unroll
  for (int e=0;e<NELEM;e++) xv += attrs[n*NELEM+e]*W_embed[e*KDIM+k];
  float yv = 0.f;
  #pragma unroll 8
  for (int k2=0;k2<KDIM;k2++) yv += __shfl(xv, k2, 64) * W_up[k2*KDIM+k];
  if (lane < 32){
    xbuf[n*KDIM+k]=xv;
    ybuf[n*KDIM+k]=yv;
  }
  if (lane == 0){
    float s=0.f;
    #pragma unroll
    for (int e=0;e<NELEM;e++) s += attrs[n*NELEM+e]*ae[e];
    e0con[n] = s;
  }
}

// ---------------------------------------------------------------- A accumulation (fused radial LUT)
__global__ void __launch_bounds__(256) node_accA_kernel(
    const int* __restrict__ row_start, const int* __restrict__ elist,
    const int* __restrict__ eidx, const float* __restrict__ shifts,
    const float* __restrict__ pos, const float* __restrict__ ybuf,
    const float* __restrict__ lut,
    float4* __restrict__ vbuf4, int* __restrict__ sndbuf, int* __restrict__ rcvbuf,
    float* __restrict__ A){
  int tid = threadIdx.x;
  int wl = tid>>6, lane = tid&63;
  int n = blockIdx.x*4 + wl;
  int k2 = lane>>1, ihalf = lane&1;
  float a0=0.f,a1=0.f,a2=0.f,a3=0.f,a4=0.f,a5=0.f,a6=0.f,a7=0.f;
  float px=pos[n*3+0], py=pos[n*3+1], pz=pos[n*3+2];
  int rs=row_start[n], re=row_start[n+1];
  for (int p=rs; p<re; ++p){
    int e = elist[p];
    int snd = eidx[e];
    float vx = px - pos[snd*3+0] + shifts[(size_t)e*3+0];
    float vy = py - pos[snd*3+1] + shifts[(size_t)e*3+1];
    float vz = pz - pos[snd*3+2] + shifts[(size_t)e*3+2];
    float r = sqrtf(vx*vx+vy*vy+vz*vz + 1e-18f);
    float invr = 1.0f/r;
    float u = r*INVR_MAX;
    float t = fminf(u,1.0f)*(float)LUTN;
    int gg = min((int)t, LUTN-1);
    float w = t - (float)gg;
    const float* rowA = lut + (size_t)gg*64;
    float rw0 = rowA[k2], rw1 = rowA[64+k2];
    float rw = rw0 + (rw1-rw0)*w;
    float y = ybuf[(size_t)snd*KDIM + k2];
    float xs = y*rw;
    float s0,s1,s2,s3,s4,s5,s6,s7,s8,s9,s10,s11,s12,s13,s14,s15;
    compute_sh16(vx*invr, vy*invr, vz*invr,
                 s0,s1,s2,s3,s4,s5,s6,s7,s8,s9,s10,s11,s12,s13,s14,s15);
    float e0 = ihalf ? s8  : s0;
    float e1 = ihalf ? s9  : s1;
    float e2 = ihalf ? s10 : s2;
    float e3 = ihalf ? s11 : s3;
    float e4 = ihalf ? s12 : s4;
    float e5 = ihalf ? s13 : s5;
    float e6 = ihalf ? s14 : s6;
    float e7 = ihalf ? s15 : s7;
    a0 = fmaf(xs, e0, a0);
    a1 = fmaf(xs, e1, a1);
    a2 = fmaf(xs, e2, a2);
    a3 = fmaf(xs, e3, a3);
    a4 = fmaf(xs, e4, a4);
    a5 = fmaf(xs, e5, a5);
    a6 = fmaf(xs, e6, a6);
    a7 = fmaf(xs, e7, a7);
    if (lane == 0){
      vbuf4[p] = make_float4(vx,vy,vz,r);
      sndbuf[p] = snd;
      rcvbuf[p] = n;
    }
  }
  float4* Ao = (float4*)(A + (size_t)n*512 + lane*8);
  Ao[0] = make_float4(a0,a1,a2,a3);
  Ao[1] = make_float4(a4,a5,a6,a7);
}

// ---------------------------------------------------------------- node B-ops
// thread = (k, node-pair n0/n1). TWO nodes per thread, but the i-dimension is
// processed in 2 sequential passes of 8 (unroll 1) so live state stays ~90 VGPR
// (R7's spill held all 16 i's x 2 nodes). LDS broadcast reads serve 4 nodes/wave:
// (544 + 64) ds_read_b128 per wave ~= 7.3k LDS cyc -> ~97 us model floor.
__global__ void __launch_bounds__(256) node_b_kernel(
    float* Abuf, const float* __restrict__ xbuf,
    const float* __restrict__ S3, const float* __restrict__ U2s,
    const float* __restrict__ c123, const float* __restrict__ Wread,
    float* __restrict__ econ){
  __shared__ float sS3[NPAIR*16];
  __shared__ float sU2[256];
  int tid = threadIdx.x;
  for (int v=tid; v<NPAIR*16; v+=256) sS3[v]=S3[v];
  if (tid < 256) sU2[tid]=U2s[tid];
  __syncthreads();
  int k = tid & 31, grp = tid >> 5;
  int n0 = blockIdx.x*16 + grp;
  int n1 = n0 + 8;
  const float inv_avg = 1.0f/16.0f;
  float aA[16], aB[16];
  float4* ArowA = (float4*)(Abuf + ((size_t)n0*KDIM + k)*NSHD);
  float4* ArowB = (float4*)(Abuf + ((size_t)n1*KDIM + k)*NSHD);
  #pragma unroll
  for (int q=0;q<4;q++){
    float4 tA = ArowA[q];
    aA[q*4+0]=tA.x*inv_avg; aA[q*4+1]=tA.y*inv_avg;
    aA[q*4+2]=tA.z*inv_avg; aA[q*4+3]=tA.w*inv_avg;
    float4 tB = ArowB[q];
    aB[q*4+0]=tB.x*inv_avg; aB[q*4+1]=tB.y*inv_avg;
    aB[q*4+2]=tB.z*inv_avg; aB[q*4+3]=tB.w*inv_avg;
  }
  float c1k=c123[k], c2k=c123[KDIM+k], c3k=c123[2*KDIM+k];
  float B2A=0.f, B3A=0.f, B2B=0.f, B3B=0.f;
  #pragma unroll 1
  for (int h=0; h<2; h++){
    float gA[8], gB[8];
    #pragma unroll
    for (int q=0;q<8;q++){ gA[q]=0.f; gB[q]=0.f; }
    int pid = 0;
    #pragma unroll
    for (int j=0;j<16;j++){
      #pragma unroll
      for (int l=j;l<16;l++){
        float paA = aA[j]*aA[l];
        float paB = aB[j]*aB[l];
        const float4* s3r = (const float4*)(sS3 + pid*16 + h*8);
        float4 c0 = s3r[0], c1 = s3r[1];
        gA[0]=fmaf(c0.x,paA,gA[0]); gB[0]=fmaf(c0.x,paB,gB[0]);
        gA[1]=fmaf(c0.y,paA,gA[1]); gB[1]=fmaf(c0.y,paB,gB[1]);
        gA[2]=fmaf(c0.z,paA,gA[2]); gB[2]=fmaf(c0.z,paB,gB[2]);
        gA[3]=fmaf(c0.w,paA,gA[3]); gB[3]=fmaf(c0.w,paB,gB[3]);
        gA[4]=fmaf(c1.x,paA,gA[4]); gB[4]=fmaf(c1.x,paB,gB[4]);
        gA[5]=fmaf(c1.y,paA,gA[5]); gB[5]=fmaf(c1.y,paB,gB[5]);
        gA[6]=fmaf(c1.z,paA,gA[6]); gB[6]=fmaf(c1.z,paB,gB[6]);
        gA[7]=fmaf(c1.w,paA,gA[7]); gB[7]=fmaf(c1.w,paB,gB[7]);
        pid++;
      }
    }
    float oA0=0.f,oA1=0.f,oA2=0.f, oB0=0.f,oB1=0.f,oB2=0.f;
    #pragma unroll
    for (int ii=0; ii<8; ii++){
      int i = h*8 + ii;
      // g2_i = U2s row i . a  (U2s symmetric, row-major float4 reads)
      const float4* u2r = (const float4*)(sU2 + i*16);
      float4 u0=u2r[0], u1=u2r[1], u2v=u2r[2], u3=u2r[3];
      float g2iA = u0.x*aA[0]+u0.y*aA[1]+u0.z*aA[2]+u0.w*aA[3]
                 + u1.x*aA[4]+u1.y*aA[5]+u1.z*aA[6]+u1.w*aA[7]
                 + u2v.x*aA[8]+u2v.y*aA[9]+u2v.z*aA[10]+u2v.w*aA[11]
                 + u3.x*aA[12]+u3.y*aA[13]+u3.z*aA[14]+u3.w*aA[15];
      float g2iB = u0.x*aB[0]+u0.y*aB[1]+u0.z*aB[2]+u0.w*aB[3]
                 + u1.x*aB[4]+u1.y*aB[5]+u1.z*aB[6]+u1.w*aB[7]
                 + u2v.x*aB[8]+u2v.y*aB[9]+u2v.z*aB[10]+u2v.w*aB[11]
                 + u3.x*aB[12]+u3.y*aB[13]+u3.z*aB[14]+u3.w*aB[15];
      B2A += aA[i]*g2iA;  B3A += aA[i]*gA[ii];
      B2B += aB[i]*g2iB;  B3B += aB[i]*gB[ii];
      float oA = (c2k*g2iA + c3k*gA[ii])*inv_avg;
      float oB = (c2k*g2iB + c3k*gB[ii])*inv_avg;
      if (i==0){ oA += c1k*inv_avg; oB += c1k*inv_avg; }
      int ph = ii&3;
      if (ph==0){ oA0=oA; oB0=oB; }
      else if (ph==1){ oA1=oA; oB1=oB; }
      else if (ph==2){ oA2=oA; oB2=oB; }
      else {
        ArowA[i>>2] = make_float4(oA0,oA1,oA2,oA);
        ArowB[i>>2] = make_float4(oB0,oB1,oB2,oB);
      }
    }
  }
  B2A *= 0.5f; B3A *= (1.0f/3.0f);
  B2B *= 0.5f; B3B *= (1.0f/3.0f);
  float wrk = Wread[k];
  float cA = aA[0]*c1k + B2A*c2k + B3A*c3k + xbuf[(size_t)n0*KDIM+k]*wrk;
  float cB = aB[0]*c1k + B2B*c2k + B3B*c3k + xbuf[(size_t)n1*KDIM+k]*wrk;
  #pragma unroll
  for (int off=1; off<32; off<<=1){
    cA += __shfl_xor(cA, off, 64);
    cB += __shfl_xor(cB, off, 64);
  }
  if (k==0){
    econ[n0] = cA;
    econ[n1] = cB;
  }
}

// ---------------------------------------------------------------- energy reduce
__global__ void reduce_e_kernel(const float* __restrict__ econ,
                                const float* __restrict__ e0con,
                                const int* __restrict__ batch,
                                float* __restrict__ out_e){
  __shared__ float part[NGRAPH];
  int tid = threadIdx.x;
  if (tid < NGRAPH) part[tid]=0.f;
  __syncthreads();
  int n = blockIdx.x*256 + tid;
  float v = econ[n] + e0con[n];
  atomicAdd(&part[batch[n]], v);
  __syncthreads();
  if (tid < NGRAPH) atomicAdd(&out_e[tid], part[tid]);
}

// ---------------------------------------------------------------- edge backward (thread-per-edge, LUT)
// NO atomics: stores per-edge gradient vector to SoA buffers (coalesced).
__global__ void __launch_bounds__(256) edge_bwd_kernel(
    const int* __restrict__ sndbuf, const int* __restrict__ rcvbuf,
    const float4* __restrict__ vbuf4, const float* __restrict__ ybuf,
    const float* __restrict__ lut, const float* __restrict__ gA,
    float* __restrict__ gvx_o, float* __restrict__ gvy_o, float* __restrict__ gvz_o){
  int p = blockIdx.x*256 + threadIdx.x;
  int snd = sndbuf[p], rcv = rcvbuf[p];
  float4 v4 = vbuf4[p];
  float vx=v4.x, vy=v4.y, vz=v4.z, r=v4.w;
  float invr = 1.0f/r;
  float ux=vx*invr, uy=vy*invr, uz=vz*invr;
  float u = r*INVR_MAX;
  float t = fminf(u,1.0f)*(float)LUTN;
  int gg = min((int)t, LUTN-1);
  float w = t - (float)gg;
  const float* rowA = lut + (size_t)gg*64;
  float s0,s1,s2,s3,s4,s5,s6,s7,s8,s9,s10,s11,s12,s13,s14,s15;
  compute_sh16(ux,uy,uz,
               s0,s1,s2,s3,s4,s5,s6,s7,s8,s9,s10,s11,s12,s13,s14,s15);
  const float4* ga4 = (const float4*)(gA + (size_t)rcv*512);
  const float4* y4  = (const float4*)(ybuf + (size_t)snd*KDIM);
  float G0=0.f,G1=0.f,G2=0.f,G3v=0.f,G4=0.f,G5=0.f,G6=0.f,G7=0.f;
  float G8=0.f,G9=0.f,G10=0.f,G11=0.f,G12=0.f,G13=0.f,G14=0.f,G15=0.f;
  float grad_r = 0.f;
  #pragma unroll
  for (int k4=0;k4<8;k4++){
    float4 r0 = *(const float4*)(rowA + k4*4);
    float4 r1 = *(const float4*)(rowA + 64 + k4*4);
    float4 d0 = *(const float4*)(rowA + 32 + k4*4);
    float4 d1 = *(const float4*)(rowA + 96 + k4*4);
    float rwv0 = r0.x+(r1.x-r0.x)*w, rwv1 = r0.y+(r1.y-r0.y)*w;
    float rwv2 = r0.z+(r1.z-r0.z)*w, rwv3 = r0.w+(r1.w-r0.w)*w;
    float dr0 = d0.x+(d1.x-d0.x)*w, dr1 = d0.y+(d1.y-d0.y)*w;
    float dr2 = d0.z+(d1.z-d0.z)*w, dr3 = d0.w+(d1.w-d0.w)*w;
    float4 yv = y4[k4];
    #pragma unroll
    for (int q=0;q<4;q++){
      int k = k4*4+q;
      float yk  = (q==0)?yv.x:((q==1)?yv.y:((q==2)?yv.z:yv.w));
      float rwq = (q==0)?rwv0:((q==1)?rwv1:((q==2)?rwv2:rwv3));
      float drq = (q==0)?dr0:((q==1)?dr1:((q==2)?dr2:dr3));
      float xsk = yk*rwq;
      float4 t0 = ga4[k*4+0];
      float4 t1 = ga4[k*4+1];
      float4 t2 = ga4[k*4+2];
      float4 t3 = ga4[k*4+3];
      float gxs = t0.x*s0+t0.y*s1+t0.z*s2+t0.w*s3
                + t1.x*s4+t1.y*s5+t1.z*s6+t1.w*s7
                + t2.x*s8+t2.y*s9+t2.z*s10+t2.w*s11
                + t3.x*s12+t3.y*s13+t3.z*s14+t3.w*s15;
      G0  = fmaf(t0.x,xsk,G0);  G1  = fmaf(t0.y,xsk,G1);
      G2  = fmaf(t0.z,xsk,G2);  G3v = fmaf(t0.w,xsk,G3v);
      G4  = fmaf(t1.x,xsk,G4);  G5  = fmaf(t1.y,xsk,G5);
      G6  = fmaf(t1.z,xsk,G6);  G7  = fmaf(t1.w,xsk,G7);
      G8  = fmaf(t2.x,xsk,G8);  G9  = fmaf(t2.y,xsk,G9);
      G10 = fmaf(t2.z,xsk,G10); G11 = fmaf(t2.w,xsk,G11);
      G12 = fmaf(t3.x,xsk,G12); G13 = fmaf(t3.y,xsk,G13);
      G14 = fmaf(t3.z,xsk,G14); G15 = fmaf(t3.w,xsk,G15);
      grad_r += gxs*yk*drq;
    }
  }
  float x_=ux, y_=uy, z_=uz;
  float x2=x_*x_, y2=y_*y_, z2=z_*z_;
  float gux = 0.48860251f*G3v
            + 1.09254843f*(y_*G4 + z_*G7)
            + 1.09254844f*x_*G8
            + 3.54026154f*x_*y_*G9
            + 2.89061144f*y_*z_*G10
            + 0.45704579f*(5.0f*z2-1.0f)*G13
            + 2.89061144f*x_*z_*G14
            + 1.77013077f*(x2-y2)*G15;
  float guy = 0.48860251f*G1
            + 1.09254843f*(x_*G4 + z_*G5)
            - 1.09254844f*y_*G8
            + 1.77013077f*(x2-y2)*G9
            + 2.89061144f*x_*z_*G10
            + 0.45704579f*(5.0f*z2-1.0f)*G11
            - 2.89061144f*y_*z_*G14
            - 3.54026154f*x_*y_*G15;
  float guz = 0.48860251f*G2
            + 1.09254843f*(y_*G5 + x_*G7)
            + 1.89234942f*z_*G6
            + 2.89061144f*x_*y_*G10
            + 4.5704579f*y_*z_*G11
            + 0.37317633f*(15.0f*z2-3.0f)*G12
            + 4.5704579f*x_*z_*G13
            + 1.44530572f*(x2-y2)*G14;
  float dotg = gux*x_ + guy*y_ + guz*z_;
  gvx_o[p] = grad_r*x_ + (gux - dotg*x_)*invr;
  gvy_o[p] = grad_r*y_ + (guy - dotg*y_)*invr;
  gvz_o[p] = grad_r*z_ + (guz - dotg*z_)*invr;
}

// ---------------------------------------------------------------- force assembly
__global__ void force_kernel(const int* __restrict__ row_start,
                             const int* __restrict__ row2_start,
                             const int* __restrict__ elist2,
                             const float* __restrict__ gvx, const float* __restrict__ gvy,
                             const float* __restrict__ gvz, float* __restrict__ F){
  int n = blockIdx.x*256 + threadIdx.x;
  float fx=0.f, fy=0.f, fz=0.f;
  int rs=row_start[n], re=row_start[n+1];
  for (int p=rs; p<re; ++p){
    fx -= gvx[p]; fy -= gvy[p]; fz -= gvz[p];
  }
  int s2=row2_start[n], e2=row2_start[n+1];
  for (int q=s2; q<e2; ++q){
    int p = elist2[q];
    fx += gvx[p]; fy += gvy[p]; fz += gvz[p];
  }
  F[n*3+0]=fx; F[n*3+1]=fy; F[n*3+2]=fz;
}

extern "C" void kernel_launch(void* const* d_in, const int* in_sizes, int n_in,
                              void* d_out, int out_size, void* d_ws, size_t ws_size,
                              hipStream_t stream){
  const float* positions       = (const float*)d_in[0];
  const float* node_attrs      = (const float*)d_in[1];
  const int*   edge_index      = (const int*)  d_in[2];
  const float* shifts          = (const float*)d_in[3];
  const int*   batch           = (const int*)  d_in[4];
  const float* atomic_energies = (const float*)d_in[6];
  const float* W_embed         = (const float*)d_in[7];
  const float* W_up            = (const float*)d_in[8];
  const float* W_r1            = (const float*)d_in[9];
  const float* b_r1            = (const float*)d_in[10];
  const float* W_r2            = (const float*)d_in[11];
  const float* U2              = (const float*)d_in[12];
  const float* U3              = (const float*)d_in[13];
  const float* Wp1             = (const float*)d_in[14];
  const float* Wp2             = (const float*)d_in[15];
  const float* Wp3             = (const float*)d_in[16];
  const float* W_read          = (const float*)d_in[17];
  float* out = (float*)d_out;

  float* Abuf  = (float*)d_ws;                        // N*512 (A, then gA in place)
  float* xbuf  = Abuf  + (size_t)NNODES*KDIM*NSHD;    // N*32
  float* ybuf  = xbuf  + (size_t)NNODES*KDIM;         // N*32
  float* lut   = ybuf  + (size_t)NNODES*KDIM;         // 2050*64
  float* S3    = lut   + (size_t)2050*64;             // 136*16 -> pad 2304
  float* U2s   = S3    + 2304;                        // 256
  float* c123  = U2s   + 256;                         // 96 -> pad 128
  float* econ  = c123  + 128;                         // N
  float* e0con = econ  + NNODES;                      // N
  float4* vbuf4 = (float4*)(e0con + NNODES);          // E float4
  float* gvx   = (float*)(vbuf4 + (size_t)NEDGES);    // E
  float* gvy   = gvx + NEDGES;                        // E
  float* gvz   = gvy + NEDGES;                        // E
  int* sndbuf  = (int*)(gvz + NEDGES);                // E
  int* rcvbuf  = sndbuf + NEDGES;                     // E
  int* cnt       = rcvbuf + NEDGES;                   // N
  int* row_start = cnt + NNODES;                      // N+1 (pad 64)
  int* woff      = row_start + NNODES + 64;           // N
  int* elist     = woff + NNODES;                     // E
  int* cnt2      = elist + NEDGES;                    // N
  int* row2      = cnt2 + NNODES;                     // N+1 (pad 64)
  int* woff2     = row2 + NNODES + 64;                // N
  int* elist2    = woff2 + NNODES;                    // E

  hipMemsetAsync(out, 0, sizeof(float)*NGRAPH, stream);
  hipMemsetAsync(cnt, 0, sizeof(int)*NNODES, stream);
  hipMemsetAsync(cnt2, 0, sizeof(int)*NNODES, stream);

  prep_kernel<<<1,256,0,stream>>>(U2,U3,Wp1,Wp2,Wp3,W_read,S3,U2s,c123);
  lut_kernel<<<(LUTN+1+255)/256,256,0,stream>>>(W_r1,b_r1,W_r2,lut);
  csr_count_kernel<<<NEDGES/256,256,0,stream>>>(edge_index, cnt);
  csr_scan_kernel<<<1,1024,0,stream>>>(cnt, row_start, woff);
  csr_scatter_kernel<<<NEDGES/256,256,0,stream>>>(edge_index, woff, elist);
  node_embed_kernel<<<NNODES/4,256,0,stream>>>(node_attrs,W_embed,W_up,atomic_energies,
                                               xbuf,ybuf,e0con);
  node_accA_kernel<<<NNODES/4,256,0,stream>>>(row_start,elist,edge_index,shifts,
                                              positions,ybuf,lut,vbuf4,sndbuf,rcvbuf,Abuf);
  // sender-CSR over CSR positions (needs sndbuf from node_accA)
  csr2_count_kernel<<<NEDGES/256,256,0,stream>>>(sndbuf, cnt2);
  csr_scan_kernel<<<1,1024,0,stream>>>(cnt2, row2, woff2);
  csr2_scatter_kernel<<<NEDGES/256,256,0,stream>>>(sndbuf, woff2, elist2);
  node_b_kernel<<<NNODES/16,256,0,stream>>>(Abuf,xbuf,S3,U2s,c123,W_read,econ);
  reduce_e_kernel<<<NNODES/256,256,0,stream>>>(econ,e0con,batch,out);
  edge_bwd_kernel<<<NEDGES/256,256,0,stream>>>(sndbuf,rcvbuf,vbuf4,ybuf,lut,Abuf,
                                               gvx,gvy,gvz);
  force_kernel<<<NNODES/256,256,0,stream>>>(row_start,row2,elist2,gvx,gvy,gvz,out+NGRAPH);
}

// Round 11
// 2785.986 us; speedup vs baseline: 1.1538x; 1.1538x over previous
//
#include <hip/hip_runtime.h>
#include <math.h>

#define NNODES 32768
#define NEDGES 524288
#define KDIM 32
#define NSHD 16
#define NB 8
#define NHID 64
#define NGRAPH 16
#define NELEM 10
#define RMAXF 5.0f
#define INVR_MAX 0.2f
#define PI_F 3.14159265358979f
#define CBES 0.632455532033676f   /* sqrt(2/R_MAX) */
#define LUTN 2048
#define NPAIR 136                 /* 16*17/2 symmetric (j<=l) pairs */

#if defined(__has_builtin)
#if __has_builtin(__builtin_amdgcn_sched_barrier)
#define SCHED_FENCE() __builtin_amdgcn_sched_barrier(0)
#endif
#endif
#ifndef SCHED_FENCE
#define SCHED_FENCE()
#endif

// 16 named outputs: keeps SH values in VGPRs (array form triggered
// PromoteAlloca -> LDS with 32-way bank conflicts, R5 post-mortem).
__device__ __forceinline__ void compute_sh16(float x, float y, float z,
    float& s0, float& s1, float& s2, float& s3,
    float& s4, float& s5, float& s6, float& s7,
    float& s8, float& s9, float& s10, float& s11,
    float& s12, float& s13, float& s14, float& s15){
  float x2=x*x, y2=y*y, z2=z*z;
  s0=0.28209479f;
  s1=0.48860251f*y;
  s2=0.48860251f*z;
  s3=0.48860251f*x;
  s4=1.09254843f*x*y;
  s5=1.09254843f*y*z;
  s6=0.31539157f*(3.0f*z2-1.0f);
  s7=1.09254843f*x*z;
  s8=0.54627422f*(x2-y2);
  s9=0.59004359f*y*(3.0f*x2-y2);
  s10=2.89061144f*x*y*z;
  s11=0.45704579f*y*(5.0f*z2-1.0f);
  s12=0.37317633f*z*(5.0f*z2-3.0f);
  s13=0.45704579f*x*(5.0f*z2-1.0f);
  s14=1.44530572f*z*(x2-y2);
  s15=0.59004359f*x*(x2-3.0f*y2);
}

// ---------------------------------------------------------------- prep
__global__ void prep_kernel(const float* __restrict__ U2, const float* __restrict__ U3,
                            const float* __restrict__ Wp1, const float* __restrict__ Wp2,
                            const float* __restrict__ Wp3, const float* __restrict__ Wread,
                            float* __restrict__ S3, float* __restrict__ U2s,
                            float* __restrict__ c123){
  int t = threadIdx.x;
  for (int v = t; v < NPAIR*16; v += 256){
    int pid = v >> 4, i = v & 15;
    int j = 0, rem = pid;
    while (rem >= 16 - j){ rem -= 16 - j; j++; }
    int l = j + rem;
    float s;
    if (j == l){
      s = U3[i*256 + j*16 + j] + U3[j*256 + i*16 + j] + U3[j*256 + j*16 + i];
    } else {
      s = U3[i*256 + j*16 + l] + U3[j*256 + i*16 + l] + U3[j*256 + l*16 + i]
        + U3[i*256 + l*16 + j] + U3[l*256 + i*16 + j] + U3[l*256 + j*16 + i];
    }
    S3[v] = s;
  }
  {
    int i = t >> 4, j = t & 15;
    U2s[t] = U2[i*16+j] + U2[j*16+i];
  }
  if (t < 96){
    int which = t >> 5, k = t & 31;
    const float* Wp = (which==0)?Wp1:((which==1)?Wp2:Wp3);
    float s = 0.f;
    for (int q=0;q<KDIM;q++) s += Wp[k*KDIM+q]*Wread[q];
    c123[t] = s;
  }
}

// ---------------------------------------------------------------- radial LUT
__global__ void lut_kernel(const float* __restrict__ W_r1, const float* __restrict__ b_r1,
                           const float* __restrict__ W_r2, float* __restrict__ lut){
  int g = blockIdx.x*256 + threadIdx.x;
  if (g > LUTN) return;
  float r = fmaxf(5.0f*(float)g/(float)LUTN, 1e-9f);
  float invr = 1.0f/r;
  float u = r*INVR_MAX;
  float cut = 0.f, dcdr = 0.f;
  if (u < 1.0f){
    float u2=u*u, u3=u2*u, u6=u3*u3;
    cut = 1.0f - 28.0f*u6 + 48.0f*u6*u - 21.0f*u6*u2;
    float u4=u2*u2, om=1.0f-u;
    dcdr = -168.0f*u4*u*om*om*INVR_MAX;
  }
  float b[NB], db[NB];
  #pragma unroll
  for (int q=0;q<NB;q++){
    float nn = (float)(q+1);
    float ang = PI_F*nn*u;
    float S = sinf(ang), C = cosf(ang);
    b[q]  = CBES*S*invr*cut;
    db[q] = CBES*invr*((PI_F*nn*INVR_MAX)*C - S*invr)*cut + CBES*S*invr*dcdr;
  }
  float Rw[KDIM], dRw[KDIM];
  #pragma unroll
  for (int k=0;k<KDIM;k++){ Rw[k]=0.f; dRw[k]=0.f; }
  for (int m=0;m<NHID;m++){
    float h = b_r1[m], dh = 0.f;
    #pragma unroll
    for (int q=0;q<NB;q++){ h += b[q]*W_r1[q*NHID+m]; dh += db[q]*W_r1[q*NHID+m]; }
    float sg = 1.0f/(1.0f+expf(-h));
    float s  = h*sg;
    float sp = sg*(1.0f + h*(1.0f-sg));
    float f  = sp*dh;
    #pragma unroll
    for (int k=0;k<KDIM;k++){
      Rw[k]  += s*W_r2[m*KDIM+k];
      dRw[k] += f*W_r2[m*KDIM+k];
    }
  }
  #pragma unroll
  for (int k=0;k<KDIM;k++){
    lut[(size_t)g*64 + k]      = Rw[k];
    lut[(size_t)g*64 + 32 + k] = dRw[k];
  }
}

// ---------------------------------------------------------------- CSR build (receiver)
__global__ void csr_count_kernel(const int* __restrict__ eidx, int* __restrict__ cnt){
  int e = blockIdx.x*256 + threadIdx.x;
  if (e < NEDGES) atomicAdd(&cnt[eidx[NEDGES + e]], 1);
}

__global__ void csr_scan_kernel(const int* __restrict__ cnt, int* __restrict__ row_start,
                                int* __restrict__ woff){
  __shared__ int part[1024];
  int t = threadIdx.x;
  int base_idx = t*32;
  int local[32];
  int s = 0;
  #pragma unroll
  for (int j=0;j<32;j++){
    int c = cnt[base_idx+j];
    local[j] = s;
    s += c;
  }
  part[t] = s;
  __syncthreads();
  for (int off=1; off<1024; off<<=1){
    int v = (t>=off) ? part[t-off] : 0;
    __syncthreads();
    part[t] += v;
    __syncthreads();
  }
  int base = (t==0) ? 0 : part[t-1];
  #pragma unroll
  for (int j=0;j<32;j++){
    int v = base + local[j];
    row_start[base_idx+j] = v;
    woff[base_idx+j] = v;
  }
  if (t==1023) row_start[NNODES] = part[1023];
}

__global__ void csr_scatter_kernel(const int* __restrict__ eidx, int* __restrict__ woff,
                                   int* __restrict__ elist){
  int e = blockIdx.x*256 + threadIdx.x;
  if (e < NEDGES){
    int rcv = eidx[NEDGES + e];
    int p = atomicAdd(&woff[rcv], 1);
    elist[p] = e;
  }
}

// ---------------------------------------------------------------- CSR build (sender, over CSR positions)
__global__ void csr2_count_kernel(const int* __restrict__ sndbuf, int* __restrict__ cnt2){
  int p = blockIdx.x*256 + threadIdx.x;
  if (p < NEDGES) atomicAdd(&cnt2[sndbuf[p]], 1);
}

__global__ void csr2_scatter_kernel(const int* __restrict__ sndbuf, int* __restrict__ woff2,
                                    int* __restrict__ elist2){
  int p = blockIdx.x*256 + threadIdx.x;
  if (p < NEDGES){
    int s = sndbuf[p];
    int slot = atomicAdd(&woff2[s], 1);
    elist2[slot] = p;
  }
}

// ---------------------------------------------------------------- node embed
__global__ void node_embed_kernel(const float* __restrict__ attrs,
                                  const float* __restrict__ W_embed,
                                  const float* __restrict__ W_up,
                                  const float* __restrict__ ae,
                                  float* __restrict__ xbuf, float* __restrict__ ybuf,
                                  float* __restrict__ e0con){
  int gtid = blockIdx.x*256 + threadIdx.x;
  int n = gtid >> 6;
  int lane = threadIdx.x & 63;
  int k = lane & 31;
  float xv = 0.f;
  #pragma unroll
  for (int e=0;e<NELEM;e++) xv += attrs[n*NELEM+e]*W_embed[e*KDIM+k];
  float yv = 0.f;
  #pragma unroll 8
  for (int k2=0;k2<KDIM;k2++) yv += __shfl(xv, k2, 64) * W_up[k2*KDIM+k];
  if (lane < 32){
    xbuf[n*KDIM+k]=xv;
    ybuf[n*KDIM+k]=yv;
  }
  if (lane == 0){
    float s=0.f;
    #pragma unroll
    for (int e=0;e<NELEM;e++) s += attrs[n*NELEM+e]*ae[e];
    e0con[n] = s;
  }
}

// ---------------------------------------------------------------- A accumulation (fused radial LUT)
__global__ void __launch_bounds__(256) node_accA_kernel(
    const int* __restrict__ row_start, const int* __restrict__ elist,
    const int* __restrict__ eidx, const float* __restrict__ shifts,
    const float* __restrict__ pos, const float* __restrict__ ybuf,
    const float* __restrict__ lut,
    float4* __restrict__ vbuf4, int* __restrict__ sndbuf, int* __restrict__ rcvbuf,
    float* __restrict__ A){
  int tid = threadIdx.x;
  int wl = tid>>6, lane = tid&63;
  int n = blockIdx.x*4 + wl;
  int k2 = lane>>1, ihalf = lane&1;
  float a0=0.f,a1=0.f,a2=0.f,a3=0.f,a4=0.f,a5=0.f,a6=0.f,a7=0.f;
  float px=pos[n*3+0], py=pos[n*3+1], pz=pos[n*3+2];
  int rs=row_start[n], re=row_start[n+1];
  for (int p=rs; p<re; ++p){
    int e = elist[p];
    int snd = eidx[e];
    float vx = px - pos[snd*3+0] + shifts[(size_t)e*3+0];
    float vy = py - pos[snd*3+1] + shifts[(size_t)e*3+1];
    float vz = pz - pos[snd*3+2] + shifts[(size_t)e*3+2];
    float r = sqrtf(vx*vx+vy*vy+vz*vz + 1e-18f);
    float invr = 1.0f/r;
    float u = r*INVR_MAX;
    float t = fminf(u,1.0f)*(float)LUTN;
    int gg = min((int)t, LUTN-1);
    float w = t - (float)gg;
    const float* rowA = lut + (size_t)gg*64;
    float rw0 = rowA[k2], rw1 = rowA[64+k2];
    float rw = rw0 + (rw1-rw0)*w;
    float y = ybuf[(size_t)snd*KDIM + k2];
    float xs = y*rw;
    float s0,s1,s2,s3,s4,s5,s6,s7,s8,s9,s10,s11,s12,s13,s14,s15;
    compute_sh16(vx*invr, vy*invr, vz*invr,
                 s0,s1,s2,s3,s4,s5,s6,s7,s8,s9,s10,s11,s12,s13,s14,s15);
    float e0 = ihalf ? s8  : s0;
    float e1 = ihalf ? s9  : s1;
    float e2 = ihalf ? s10 : s2;
    float e3 = ihalf ? s11 : s3;
    float e4 = ihalf ? s12 : s4;
    float e5 = ihalf ? s13 : s5;
    float e6 = ihalf ? s14 : s6;
    float e7 = ihalf ? s15 : s7;
    a0 = fmaf(xs, e0, a0);
    a1 = fmaf(xs, e1, a1);
    a2 = fmaf(xs, e2, a2);
    a3 = fmaf(xs, e3, a3);
    a4 = fmaf(xs, e4, a4);
    a5 = fmaf(xs, e5, a5);
    a6 = fmaf(xs, e6, a6);
    a7 = fmaf(xs, e7, a7);
    if (lane == 0){
      vbuf4[p] = make_float4(vx,vy,vz,r);
      sndbuf[p] = snd;
      rcvbuf[p] = n;
    }
  }
  float4* Ao = (float4*)(A + (size_t)n*512 + lane*8);
  Ao[0] = make_float4(a0,a1,a2,a3);
  Ao[1] = make_float4(a4,a5,a6,a7);
}

// ---------------------------------------------------------------- node B-ops
// thread = (k, node-pair n0/n1): 2 nodes/thread, i processed in FOUR passes of 4
// (runtime h, unroll 1) -> live state aA[16]+aB[16]+g{A,B}[4] ~= 45 regs.
// sched_barrier(0) per j-group caps the LDS load-hoist window (R10 spilled to
// 256 VGPR because the scheduler hoisted a whole pass's 272 loads).
__global__ void __launch_bounds__(256) node_b_kernel(
    float* Abuf, const float* __restrict__ xbuf,
    const float* __restrict__ S3, const float* __restrict__ U2s,
    const float* __restrict__ c123, const float* __restrict__ Wread,
    float* __restrict__ econ){
  __shared__ float sS3[NPAIR*16];
  __shared__ float sU2[256];
  int tid = threadIdx.x;
  for (int v=tid; v<NPAIR*16; v+=256) sS3[v]=S3[v];
  if (tid < 256) sU2[tid]=U2s[tid];
  __syncthreads();
  int k = tid & 31, grp = tid >> 5;
  int n0 = blockIdx.x*16 + grp;
  int n1 = n0 + 8;
  const float inv_avg = 1.0f/16.0f;
  float aA[16], aB[16];
  float4* ArowA = (float4*)(Abuf + ((size_t)n0*KDIM + k)*NSHD);
  float4* ArowB = (float4*)(Abuf + ((size_t)n1*KDIM + k)*NSHD);
  #pragma unroll
  for (int q=0;q<4;q++){
    float4 tA = ArowA[q];
    aA[q*4+0]=tA.x*inv_avg; aA[q*4+1]=tA.y*inv_avg;
    aA[q*4+2]=tA.z*inv_avg; aA[q*4+3]=tA.w*inv_avg;
    float4 tB = ArowB[q];
    aB[q*4+0]=tB.x*inv_avg; aB[q*4+1]=tB.y*inv_avg;
    aB[q*4+2]=tB.z*inv_avg; aB[q*4+3]=tB.w*inv_avg;
  }
  float c1k=c123[k], c2k=c123[KDIM+k], c3k=c123[2*KDIM+k];
  float SB2A=0.f, SB3A=0.f, SB2B=0.f, SB3B=0.f;   // sum_i a_i g2_i / a_i g3_i
  #pragma unroll 1
  for (int h=0; h<4; h++){
    // ---- g3 components i = h*4 .. h*4+3 (one b128 per pair)
    float gA0=0.f,gA1=0.f,gA2=0.f,gA3=0.f;
    float gB0=0.f,gB1=0.f,gB2=0.f,gB3=0.f;
    const float* s3h = sS3 + h*4;
    int pid = 0;
    #pragma unroll
    for (int j=0;j<16;j++){
      #pragma unroll
      for (int l=j;l<16;l++){
        float4 c = *(const float4*)(s3h + pid*16);
        float paA = aA[j]*aA[l];
        float paB = aB[j]*aB[l];
        gA0=fmaf(c.x,paA,gA0); gA1=fmaf(c.y,paA,gA1);
        gA2=fmaf(c.z,paA,gA2); gA3=fmaf(c.w,paA,gA3);
        gB0=fmaf(c.x,paB,gB0); gB1=fmaf(c.y,paB,gB1);
        gB2=fmaf(c.z,paB,gB2); gB3=fmaf(c.w,paB,gB3);
        pid++;
      }
      SCHED_FENCE();
    }
    // ---- g2 components i = h*4 .. h*4+3 (column-block of symmetric U2s)
    float g2A0=0.f,g2A1=0.f,g2A2=0.f,g2A3=0.f;
    float g2B0=0.f,g2B1=0.f,g2B2=0.f,g2B3=0.f;
    const float* u2h = sU2 + h*4;
    #pragma unroll
    for (int j=0;j<16;j++){
      float4 u = *(const float4*)(u2h + j*16);
      float ajA=aA[j], ajB=aB[j];
      g2A0=fmaf(u.x,ajA,g2A0); g2A1=fmaf(u.y,ajA,g2A1);
      g2A2=fmaf(u.z,ajA,g2A2); g2A3=fmaf(u.w,ajA,g2A3);
      g2B0=fmaf(u.x,ajB,g2B0); g2B1=fmaf(u.y,ajB,g2B1);
      g2B2=fmaf(u.z,ajB,g2B2); g2B3=fmaf(u.w,ajB,g2B3);
    }
    SCHED_FENCE();
    // ---- a[h*4+q] via wave-uniform branch on h (no dynamic reg indexing)
    float x0A,x1A,x2A,x3A, x0B,x1B,x2B,x3B;
    if (h==0){ x0A=aA[0];  x1A=aA[1];  x2A=aA[2];  x3A=aA[3];
               x0B=aB[0];  x1B=aB[1];  x2B=aB[2];  x3B=aB[3]; }
    else if (h==1){ x0A=aA[4];  x1A=aA[5];  x2A=aA[6];  x3A=aA[7];
                    x0B=aB[4];  x1B=aB[5];  x2B=aB[6];  x3B=aB[7]; }
    else if (h==2){ x0A=aA[8];  x1A=aA[9];  x2A=aA[10]; x3A=aA[11];
                    x0B=aB[8];  x1B=aB[9];  x2B=aB[10]; x3B=aB[11]; }
    else { x0A=aA[12]; x1A=aA[13]; x2A=aA[14]; x3A=aA[15];
           x0B=aB[12]; x1B=aB[13]; x2B=aB[14]; x3B=aB[15]; }
    SB2A += x0A*g2A0 + x1A*g2A1 + x2A*g2A2 + x3A*g2A3;
    SB3A += x0A*gA0  + x1A*gA1  + x2A*gA2  + x3A*gA3;
    SB2B += x0B*g2B0 + x1B*g2B1 + x2B*g2B2 + x3B*g2B3;
    SB3B += x0B*gB0  + x1B*gB1  + x2B*gB2  + x3B*gB3;
    // ---- gA output row h (in place over A)
    float oA0 = (c2k*g2A0 + c3k*gA0)*inv_avg;
    float oA1 = (c2k*g2A1 + c3k*gA1)*inv_avg;
    float oA2 = (c2k*g2A2 + c3k*gA2)*inv_avg;
    float oA3 = (c2k*g2A3 + c3k*gA3)*inv_avg;
    float oB0 = (c2k*g2B0 + c3k*gB0)*inv_avg;
    float oB1 = (c2k*g2B1 + c3k*gB1)*inv_avg;
    float oB2 = (c2k*g2B2 + c3k*gB2)*inv_avg;
    float oB3 = (c2k*g2B3 + c3k*gB3)*inv_avg;
    if (h==0){ oA0 += c1k*inv_avg; oB0 += c1k*inv_avg; }
    ArowA[h] = make_float4(oA0,oA1,oA2,oA3);
    ArowB[h] = make_float4(oB0,oB1,oB2,oB3);
  }
  float wrk = Wread[k];
  float cA = aA[0]*c1k + 0.5f*SB2A*c2k + (1.0f/3.0f)*SB3A*c3k
           + xbuf[(size_t)n0*KDIM+k]*wrk;
  float cB = aB[0]*c1k + 0.5f*SB2B*c2k + (1.0f/3.0f)*SB3B*c3k
           + xbuf[(size_t)n1*KDIM+k]*wrk;
  #pragma unroll
  for (int off=1; off<32; off<<=1){
    cA += __shfl_xor(cA, off, 64);
    cB += __shfl_xor(cB, off, 64);
  }
  if (k==0){
    econ[n0] = cA;
    econ[n1] = cB;
  }
}

// ---------------------------------------------------------------- energy reduce
__global__ void reduce_e_kernel(const float* __restrict__ econ,
                                const float* __restrict__ e0con,
                                const int* __restrict__ batch,
                                float* __restrict__ out_e){
  __shared__ float part[NGRAPH];
  int tid = threadIdx.x;
  if (tid < NGRAPH) part[tid]=0.f;
  __syncthreads();
  int n = blockIdx.x*256 + tid;
  float v = econ[n] + e0con[n];
  atomicAdd(&part[batch[n]], v);
  __syncthreads();
  if (tid < NGRAPH) atomicAdd(&out_e[tid], part[tid]);
}

// ---------------------------------------------------------------- edge backward (thread-per-edge, LUT)
// NO atomics: stores per-edge gradient vector to SoA buffers (coalesced).
__global__ void __launch_bounds__(256) edge_bwd_kernel(
    const int* __restrict__ sndbuf, const int* __restrict__ rcvbuf,
    const float4* __restrict__ vbuf4, const float* __restrict__ ybuf,
    const float* __restrict__ lut, const float* __restrict__ gA,
    float* __restrict__ gvx_o, float* __restrict__ gvy_o, float* __restrict__ gvz_o){
  int p = blockIdx.x*256 + threadIdx.x;
  int snd = sndbuf[p], rcv = rcvbuf[p];
  float4 v4 = vbuf4[p];
  float vx=v4.x, vy=v4.y, vz=v4.z, r=v4.w;
  float invr = 1.0f/r;
  float ux=vx*invr, uy=vy*invr, uz=vz*invr;
  float u = r*INVR_MAX;
  float t = fminf(u,1.0f)*(float)LUTN;
  int gg = min((int)t, LUTN-1);
  float w = t - (float)gg;
  const float* rowA = lut + (size_t)gg*64;
  float s0,s1,s2,s3,s4,s5,s6,s7,s8,s9,s10,s11,s12,s13,s14,s15;
  compute_sh16(ux,uy,uz,
               s0,s1,s2,s3,s4,s5,s6,s7,s8,s9,s10,s11,s12,s13,s14,s15);
  const float4* ga4 = (const float4*)(gA + (size_t)rcv*512);
  const float4* y4  = (const float4*)(ybuf + (size_t)snd*KDIM);
  float G0=0.f,G1=0.f,G2=0.f,G3v=0.f,G4=0.f,G5=0.f,G6=0.f,G7=0.f;
  float G8=0.f,G9=0.f,G10=0.f,G11=0.f,G12=0.f,G13=0.f,G14=0.f,G15=0.f;
  float grad_r = 0.f;
  #pragma unroll
  for (int k4=0;k4<8;k4++){
    float4 r0 = *(const float4*)(rowA + k4*4);
    float4 r1 = *(const float4*)(rowA + 64 + k4*4);
    float4 d0 = *(const float4*)(rowA + 32 + k4*4);
    float4 d1 = *(const float4*)(rowA + 96 + k4*4);
    float rwv0 = r0.x+(r1.x-r0.x)*w, rwv1 = r0.y+(r1.y-r0.y)*w;
    float rwv2 = r0.z+(r1.z-r0.z)*w, rwv3 = r0.w+(r1.w-r0.w)*w;
    float dr0 = d0.x+(d1.x-d0.x)*w, dr1 = d0.y+(d1.y-d0.y)*w;
    float dr2 = d0.z+(d1.z-d0.z)*w, dr3 = d0.w+(d1.w-d0.w)*w;
    float4 yv = y4[k4];
    #pragma unroll
    for (int q=0;q<4;q++){
      int k = k4*4+q;
      float yk  = (q==0)?yv.x:((q==1)?yv.y:((q==2)?yv.z:yv.w));
      float rwq = (q==0)?rwv0:((q==1)?rwv1:((q==2)?rwv2:rwv3));
      float drq = (q==0)?dr0:((q==1)?dr1:((q==2)?dr2:dr3));
      float xsk = yk*rwq;
      float4 t0 = ga4[k*4+0];
      float4 t1 = ga4[k*4+1];
      float4 t2 = ga4[k*4+2];
      float4 t3 = ga4[k*4+3];
      float gxs = t0.x*s0+t0.y*s1+t0.z*s2+t0.w*s3
                + t1.x*s4+t1.y*s5+t1.z*s6+t1.w*s7
                + t2.x*s8+t2.y*s9+t2.z*s10+t2.w*s11
                + t3.x*s12+t3.y*s13+t3.z*s14+t3.w*s15;
      G0  = fmaf(t0.x,xsk,G0);  G1  = fmaf(t0.y,xsk,G1);
      G2  = fmaf(t0.z,xsk,G2);  G3v = fmaf(t0.w,xsk,G3v);
      G4  = fmaf(t1.x,xsk,G4);  G5  = fmaf(t1.y,xsk,G5);
      G6  = fmaf(t1.z,xsk,G6);  G7  = fmaf(t1.w,xsk,G7);
      G8  = fmaf(t2.x,xsk,G8);  G9  = fmaf(t2.y,xsk,G9);
      G10 = fmaf(t2.z,xsk,G10); G11 = fmaf(t2.w,xsk,G11);
      G12 = fmaf(t3.x,xsk,G12); G13 = fmaf(t3.y,xsk,G13);
      G14 = fmaf(t3.z,xsk,G14); G15 = fmaf(t3.w,xsk,G15);
      grad_r += gxs*yk*drq;
    }
  }
  float x_=ux, y_=uy, z_=uz;
  float x2=x_*x_, y2=y_*y_, z2=z_*z_;
  float gux = 0.48860251f*G3v
            + 1.09254843f*(y_*G4 + z_*G7)
            + 1.09254844f*x_*G8
            + 3.54026154f*x_*y_*G9
            + 2.89061144f*y_*z_*G10
            + 0.45704579f*(5.0f*z2-1.0f)*G13
            + 2.89061144f*x_*z_*G14
            + 1.77013077f*(x2-y2)*G15;
  float guy = 0.48860251f*G1
            + 1.09254843f*(x_*G4 + z_*G5)
            - 1.09254844f*y_*G8
            + 1.77013077f*(x2-y2)*G9
            + 2.89061144f*x_*z_*G10
            + 0.45704579f*(5.0f*z2-1.0f)*G11
            - 2.89061144f*y_*z_*G14
            - 3.54026154f*x_*y_*G15;
  float guz = 0.48860251f*G2
            + 1.09254843f*(y_*G5 + x_*G7)
            + 1.89234942f*z_*G6
            + 2.89061144f*x_*y_*G10
            + 4.5704579f*y_*z_*G11
            + 0.37317633f*(15.0f*z2-3.0f)*G12
            + 4.5704579f*x_*z_*G13
            + 1.44530572f*(x2-y2)*G14;
  float dotg = gux*x_ + guy*y_ + guz*z_;
  gvx_o[p] = grad_r*x_ + (gux - dotg*x_)*invr;
  gvy_o[p] = grad_r*y_ + (guy - dotg*y_)*invr;
  gvz_o[p] = grad_r*z_ + (guz - dotg*z_)*invr;
}

// ---------------------------------------------------------------- force assembly
__global__ void force_kernel(const int* __restrict__ row_start,
                             const int* __restrict__ row2_start,
                             const int* __restrict__ elist2,
                             const float* __restrict__ gvx, const float* __restrict__ gvy,
                             const float* __restrict__ gvz, float* __restrict__ F){
  int n = blockIdx.x*256 + threadIdx.x;
  float fx=0.f, fy=0.f, fz=0.f;
  int rs=row_start[n], re=row_start[n+1];
  for (int p=rs; p<re; ++p){
    fx -= gvx[p]; fy -= gvy[p]; fz -= gvz[p];
  }
  int s2=row2_start[n], e2=row2_start[n+1];
  for (int q=s2; q<e2; ++q){
    int p = elist2[q];
    fx += gvx[p]; fy += gvy[p]; fz += gvz[p];
  }
  F[n*3+0]=fx; F[n*3+1]=fy; F[n*3+2]=fz;
}

extern "C" void kernel_launch(void* const* d_in, const int* in_sizes, int n_in,
                              void* d_out, int out_size, void* d_ws, size_t ws_size,
                              hipStream_t stream){
  const float* positions       = (const float*)d_in[0];
  const float* node_attrs      = (const float*)d_in[1];
  const int*   edge_index      = (const int*)  d_in[2];
  const float* shifts          = (const float*)d_in[3];
  const int*   batch           = (const int*)  d_in[4];
  const float* atomic_energies = (const float*)d_in[6];
  const float* W_embed         = (const float*)d_in[7];
  const float* W_up            = (const float*)d_in[8];
  const float* W_r1            = (const float*)d_in[9];
  const float* b_r1            = (const float*)d_in[10];
  const float* W_r2            = (const float*)d_in[11];
  const float* U2              = (const float*)d_in[12];
  const float* U3              = (const float*)d_in[13];
  const float* Wp1             = (const float*)d_in[14];
  const float* Wp2             = (const float*)d_in[15];
  const float* Wp3             = (const float*)d_in[16];
  const float* W_read          = (const float*)d_in[17];
  float* out = (float*)d_out;

  float* Abuf  = (float*)d_ws;                        // N*512 (A, then gA in place)
  float* xbuf  = Abuf  + (size_t)NNODES*KDIM*NSHD;    // N*32
  float* ybuf  = xbuf  + (size_t)NNODES*KDIM;         // N*32
  float* lut   = ybuf  + (size_t)NNODES*KDIM;         // 2050*64
  float* S3    = lut   + (size_t)2050*64;             // 136*16 -> pad 2304
  float* U2s   = S3    + 2304;                        // 256
  float* c123  = U2s   + 256;                         // 96 -> pad 128
  float* econ  = c123  + 128;                         // N
  float* e0con = econ  + NNODES;                      // N
  float4* vbuf4 = (float4*)(e0con + NNODES);          // E float4
  float* gvx   = (float*)(vbuf4 + (size_t)NEDGES);    // E
  float* gvy   = gvx + NEDGES;                        // E
  float* gvz   = gvy + NEDGES;                        // E
  int* sndbuf  = (int*)(gvz + NEDGES);                // E
  int* rcvbuf  = sndbuf + NEDGES;                     // E
  int* cnt       = rcvbuf + NEDGES;                   // N
  int* row_start = cnt + NNODES;                      // N+1 (pad 64)
  int* woff      = row_start + NNODES + 64;           // N
  int* elist     = woff + NNODES;                     // E
  int* cnt2      = elist + NEDGES;                    // N
  int* row2      = cnt2 + NNODES;                     // N+1 (pad 64)
  int* woff2     = row2 + NNODES + 64;                // N
  int* elist2    = woff2 + NNODES;                    // E

  hipMemsetAsync(out, 0, sizeof(float)*NGRAPH, stream);
  hipMemsetAsync(cnt, 0, sizeof(int)*NNODES, stream);
  hipMemsetAsync(cnt2, 0, sizeof(int)*NNODES, stream);

  prep_kernel<<<1,256,0,stream>>>(U2,U3,Wp1,Wp2,Wp3,W_read,S3,U2s,c123);
  lut_kernel<<<(LUTN+1+255)/256,256,0,stream>>>(W_r1,b_r1,W_r2,lut);
  csr_count_kernel<<<NEDGES/256,256,0,stream>>>(edge_index, cnt);
  csr_scan_kernel<<<1,1024,0,stream>>>(cnt, row_start, woff);
  csr_scatter_kernel<<<NEDGES/256,256,0,stream>>>(edge_index, woff, elist);
  node_embed_kernel<<<NNODES/4,256,0,stream>>>(node_attrs,W_embed,W_up,atomic_energies,
                                               xbuf,ybuf,e0con);
  node_accA_kernel<<<NNODES/4,256,0,stream>>>(row_start,elist,edge_index,shifts,
                                              positions,ybuf,lut,vbuf4,sndbuf,rcvbuf,Abuf);
  // sender-CSR over CSR positions (needs sndbuf from node_accA)
  csr2_count_kernel<<<NEDGES/256,256,0,stream>>>(sndbuf, cnt2);
  csr_scan_kernel<<<1,1024,0,stream>>>(cnt2, row2, woff2);
  csr2_scatter_kernel<<<NEDGES/256,256,0,stream>>>(sndbuf, woff2, elist2);
  node_b_kernel<<<NNODES/16,256,0,stream>>>(Abuf,xbuf,S3,U2s,c123,W_read,econ);
  reduce_e_kernel<<<NNODES/256,256,0,stream>>>(econ,e0con,batch,out);
  edge_bwd_kernel<<<NEDGES/256,256,0,stream>>>(sndbuf,rcvbuf,vbuf4,ybuf,lut,Abuf,
                                               gvx,gvy,gvz);
  force_kernel<<<NNODES/256,256,0,stream>>>(row_start,row2,elist2,gvx,gvy,gvz,out+NGRAPH);
}

// Round 12
// 712.693 us; speedup vs baseline: 4.5103x; 3.9091x over previous
//
#include <hip/hip_runtime.h>
#include <math.h>

#define NNODES 32768
#define NEDGES 524288
#define KDIM 32
#define NSHD 16
#define NB 8
#define NHID 64
#define NGRAPH 16
#define NELEM 10
#define RMAXF 5.0f
#define INVR_MAX 0.2f
#define PI_F 3.14159265358979f
#define CBES 0.632455532033676f   /* sqrt(2/R_MAX) */
#define LUTN 2048
#define NPAIR 136                 /* 16*17/2 symmetric (j<=l) pairs */

// 16 named outputs: keeps SH values in VGPRs (array form triggered
// PromoteAlloca -> LDS with 32-way bank conflicts, R5 post-mortem).
__device__ __forceinline__ void compute_sh16(float x, float y, float z,
    float& s0, float& s1, float& s2, float& s3,
    float& s4, float& s5, float& s6, float& s7,
    float& s8, float& s9, float& s10, float& s11,
    float& s12, float& s13, float& s14, float& s15){
  float x2=x*x, y2=y*y, z2=z*z;
  s0=0.28209479f;
  s1=0.48860251f*y;
  s2=0.48860251f*z;
  s3=0.48860251f*x;
  s4=1.09254843f*x*y;
  s5=1.09254843f*y*z;
  s6=0.31539157f*(3.0f*z2-1.0f);
  s7=1.09254843f*x*z;
  s8=0.54627422f*(x2-y2);
  s9=0.59004359f*y*(3.0f*x2-y2);
  s10=2.89061144f*x*y*z;
  s11=0.45704579f*y*(5.0f*z2-1.0f);
  s12=0.37317633f*z*(5.0f*z2-3.0f);
  s13=0.45704579f*x*(5.0f*z2-1.0f);
  s14=1.44530572f*z*(x2-y2);
  s15=0.59004359f*x*(x2-3.0f*y2);
}

// ---------------------------------------------------------------- prep
__global__ void prep_kernel(const float* __restrict__ U2, const float* __restrict__ U3,
                            const float* __restrict__ Wp1, const float* __restrict__ Wp2,
                            const float* __restrict__ Wp3, const float* __restrict__ Wread,
                            float* __restrict__ S3, float* __restrict__ U2s,
                            float* __restrict__ c123){
  int t = threadIdx.x;
  for (int v = t; v < NPAIR*16; v += 256){
    int pid = v >> 4, i = v & 15;
    int j = 0, rem = pid;
    while (rem >= 16 - j){ rem -= 16 - j; j++; }
    int l = j + rem;
    float s;
    if (j == l){
      s = U3[i*256 + j*16 + j] + U3[j*256 + i*16 + j] + U3[j*256 + j*16 + i];
    } else {
      s = U3[i*256 + j*16 + l] + U3[j*256 + i*16 + l] + U3[j*256 + l*16 + i]
        + U3[i*256 + l*16 + j] + U3[l*256 + i*16 + j] + U3[l*256 + j*16 + i];
    }
    S3[v] = s;
  }
  {
    int i = t >> 4, j = t & 15;
    U2s[t] = U2[i*16+j] + U2[j*16+i];
  }
  if (t < 96){
    int which = t >> 5, k = t & 31;
    const float* Wp = (which==0)?Wp1:((which==1)?Wp2:Wp3);
    float s = 0.f;
    for (int q=0;q<KDIM;q++) s += Wp[k*KDIM+q]*Wread[q];
    c123[t] = s;
  }
}

// ---------------------------------------------------------------- radial LUT
__global__ void lut_kernel(const float* __restrict__ W_r1, const float* __restrict__ b_r1,
                           const float* __restrict__ W_r2, float* __restrict__ lut){
  int g = blockIdx.x*256 + threadIdx.x;
  if (g > LUTN) return;
  float r = fmaxf(5.0f*(float)g/(float)LUTN, 1e-9f);
  float invr = 1.0f/r;
  float u = r*INVR_MAX;
  float cut = 0.f, dcdr = 0.f;
  if (u < 1.0f){
    float u2=u*u, u3=u2*u, u6=u3*u3;
    cut = 1.0f - 28.0f*u6 + 48.0f*u6*u - 21.0f*u6*u2;
    float u4=u2*u2, om=1.0f-u;
    dcdr = -168.0f*u4*u*om*om*INVR_MAX;
  }
  float b[NB], db[NB];
  #pragma unroll
  for (int q=0;q<NB;q++){
    float nn = (float)(q+1);
    float ang = PI_F*nn*u;
    float S = sinf(ang), C = cosf(ang);
    b[q]  = CBES*S*invr*cut;
    db[q] = CBES*invr*((PI_F*nn*INVR_MAX)*C - S*invr)*cut + CBES*S*invr*dcdr;
  }
  float Rw[KDIM], dRw[KDIM];
  #pragma unroll
  for (int k=0;k<KDIM;k++){ Rw[k]=0.f; dRw[k]=0.f; }
  for (int m=0;m<NHID;m++){
    float h = b_r1[m], dh = 0.f;
    #pragma unroll
    for (int q=0;q<NB;q++){ h += b[q]*W_r1[q*NHID+m]; dh += db[q]*W_r1[q*NHID+m]; }
    float sg = 1.0f/(1.0f+expf(-h));
    float s  = h*sg;
    float sp = sg*(1.0f + h*(1.0f-sg));
    float f  = sp*dh;
    #pragma unroll
    for (int k=0;k<KDIM;k++){
      Rw[k]  += s*W_r2[m*KDIM+k];
      dRw[k] += f*W_r2[m*KDIM+k];
    }
  }
  #pragma unroll
  for (int k=0;k<KDIM;k++){
    lut[(size_t)g*64 + k]      = Rw[k];
    lut[(size_t)g*64 + 32 + k] = dRw[k];
  }
}

// ---------------------------------------------------------------- CSR: count both sides in one pass
__global__ void count_kernel(const int* __restrict__ eidx,
                             int* __restrict__ cnt, int* __restrict__ cnt2){
  int e = blockIdx.x*256 + threadIdx.x;
  atomicAdd(&cnt[eidx[NEDGES + e]], 1);   // receiver
  atomicAdd(&cnt2[eidx[e]], 1);           // sender
}

// exclusive scan over NNODES counts; grid=2 handles both CSRs
__global__ void scan2_kernel(const int* __restrict__ cntA, int* __restrict__ rowA,
                             int* __restrict__ woffA,
                             const int* __restrict__ cntB, int* __restrict__ rowB,
                             int* __restrict__ woffB){
  const int* cnt = blockIdx.x ? cntB : cntA;
  int* row_start = blockIdx.x ? rowB : rowA;
  int* woff      = blockIdx.x ? woffB : woffA;
  __shared__ int part[1024];
  int t = threadIdx.x;
  int base_idx = t*32;
  int local[32];
  int s = 0;
  #pragma unroll
  for (int j=0;j<32;j++){
    int c = cnt[base_idx+j];
    local[j] = s;
    s += c;
  }
  part[t] = s;
  __syncthreads();
  for (int off=1; off<1024; off<<=1){
    int v = (t>=off) ? part[t-off] : 0;
    __syncthreads();
    part[t] += v;
    __syncthreads();
  }
  int base = (t==0) ? 0 : part[t-1];
  #pragma unroll
  for (int j=0;j<32;j++){
    int v = base + local[j];
    row_start[base_idx+j] = v;
    woff[base_idx+j] = v;
  }
  if (t==1023) row_start[NNODES] = part[1023];
}

// ---------------------------------------------------------------- scatter + edge geometry (fused)
// thread per edge: assign CSR position p (rcv-sorted), compute v/r once, write
// vbuf4[p]/sndbuf[p]/rcvbuf[p] and pos_of_e[e] (for the sender-CSR).
__global__ void scatter_geom_kernel(const int* __restrict__ eidx,
                                    const float* __restrict__ shifts,
                                    const float* __restrict__ pos,
                                    int* __restrict__ woff, int* __restrict__ pos_of_e,
                                    float4* __restrict__ vbuf4,
                                    int* __restrict__ sndbuf, int* __restrict__ rcvbuf){
  int e = blockIdx.x*256 + threadIdx.x;
  int snd = eidx[e], rcv = eidx[NEDGES + e];
  int p = atomicAdd(&woff[rcv], 1);
  float vx = pos[rcv*3+0] - pos[snd*3+0] + shifts[(size_t)e*3+0];
  float vy = pos[rcv*3+1] - pos[snd*3+1] + shifts[(size_t)e*3+1];
  float vz = pos[rcv*3+2] - pos[snd*3+2] + shifts[(size_t)e*3+2];
  float r = sqrtf(vx*vx+vy*vy+vz*vz + 1e-18f);
  vbuf4[p] = make_float4(vx,vy,vz,r);
  sndbuf[p] = snd;
  rcvbuf[p] = rcv;
  pos_of_e[e] = p;
}

// sender-CSR scatter: elist2 lists CSR positions grouped by sender
__global__ void csr2_scatter_kernel(const int* __restrict__ eidx,
                                    const int* __restrict__ pos_of_e,
                                    int* __restrict__ woff2, int* __restrict__ elist2){
  int e = blockIdx.x*256 + threadIdx.x;
  int s = eidx[e];
  int slot = atomicAdd(&woff2[s], 1);
  elist2[slot] = pos_of_e[e];
}

// ---------------------------------------------------------------- node embed
__global__ void node_embed_kernel(const float* __restrict__ attrs,
                                  const float* __restrict__ W_embed,
                                  const float* __restrict__ W_up,
                                  const float* __restrict__ ae,
                                  float* __restrict__ xbuf, float* __restrict__ ybuf,
                                  float* __restrict__ e0con){
  int gtid = blockIdx.x*256 + threadIdx.x;
  int n = gtid >> 6;
  int lane = threadIdx.x & 63;
  int k = lane & 31;
  float xv = 0.f;
  #pragma unroll
  for (int e=0;e<NELEM;e++) xv += attrs[n*NELEM+e]*W_embed[e*KDIM+k];
  float yv = 0.f;
  #pragma unroll 8
  for (int k2=0;k2<KDIM;k2++) yv += __shfl(xv, k2, 64) * W_up[k2*KDIM+k];
  if (lane < 32){
    xbuf[n*KDIM+k]=xv;
    ybuf[n*KDIM+k]=yv;
  }
  if (lane == 0){
    float s=0.f;
    #pragma unroll
    for (int e=0;e<NELEM;e++) s += attrs[n*NELEM+e]*ae[e];
    e0con[n] = s;
  }
}

// ---------------------------------------------------------------- A accumulation
// wave per node; streams vbuf4/sndbuf at loop-independent addresses (pipelined
// loads), single dependent gather (ybuf). Geometry precomputed in scatter_geom.
__global__ void __launch_bounds__(256) node_accA_kernel(
    const int* __restrict__ row_start, const float4* __restrict__ vbuf4,
    const int* __restrict__ sndbuf, const float* __restrict__ ybuf,
    const float* __restrict__ lut, float* __restrict__ A){
  int tid = threadIdx.x;
  int wl = tid>>6, lane = tid&63;
  int n = blockIdx.x*4 + wl;
  int k2 = lane>>1, ihalf = lane&1;
  float a0=0.f,a1=0.f,a2=0.f,a3=0.f,a4=0.f,a5=0.f,a6=0.f,a7=0.f;
  int rs=row_start[n], re=row_start[n+1];
  for (int p=rs; p<re; ++p){
    float4 v4 = vbuf4[p];
    int snd = sndbuf[p];
    float r = v4.w;
    float invr = 1.0f/r;
    float u = r*INVR_MAX;
    float t = fminf(u,1.0f)*(float)LUTN;
    int gg = min((int)t, LUTN-1);
    float w = t - (float)gg;
    const float* rowA = lut + (size_t)gg*64;
    float rw0 = rowA[k2], rw1 = rowA[64+k2];
    float rw = rw0 + (rw1-rw0)*w;
    float y = ybuf[(size_t)snd*KDIM + k2];
    float xs = y*rw;
    float s0,s1,s2,s3,s4,s5,s6,s7,s8,s9,s10,s11,s12,s13,s14,s15;
    compute_sh16(v4.x*invr, v4.y*invr, v4.z*invr,
                 s0,s1,s2,s3,s4,s5,s6,s7,s8,s9,s10,s11,s12,s13,s14,s15);
    float e0 = ihalf ? s8  : s0;
    float e1 = ihalf ? s9  : s1;
    float e2 = ihalf ? s10 : s2;
    float e3 = ihalf ? s11 : s3;
    float e4 = ihalf ? s12 : s4;
    float e5 = ihalf ? s13 : s5;
    float e6 = ihalf ? s14 : s6;
    float e7 = ihalf ? s15 : s7;
    a0 = fmaf(xs, e0, a0);
    a1 = fmaf(xs, e1, a1);
    a2 = fmaf(xs, e2, a2);
    a3 = fmaf(xs, e3, a3);
    a4 = fmaf(xs, e4, a4);
    a5 = fmaf(xs, e5, a5);
    a6 = fmaf(xs, e6, a6);
    a7 = fmaf(xs, e7, a7);
  }
  float4* Ao = (float4*)(A + (size_t)n*512 + lane*8);
  Ao[0] = make_float4(a0,a1,a2,a3);
  Ao[1] = make_float4(a4,a5,a6,a7);
}

// ---------------------------------------------------------------- node B-ops
// thread = (node,k), ONE node per thread (2-item variants spill: R7/R10/R11 all
// hit 256 VGPR + GB-scale scratch; this shape is 144 VGPR, proven 246 us).
// LDS-staged coefficients, same-address broadcast ds_read_b128.
__global__ void __launch_bounds__(256) node_b_kernel(
    float* Abuf, const float* __restrict__ xbuf,
    const float* __restrict__ S3, const float* __restrict__ U2s,
    const float* __restrict__ c123, const float* __restrict__ Wread,
    float* __restrict__ econ){
  __shared__ float sS3[NPAIR*16];
  __shared__ float sU2[256];
  int tid = threadIdx.x;
  for (int v=tid; v<NPAIR*16; v+=256) sS3[v]=S3[v];
  if (tid < 256) sU2[tid]=U2s[tid];
  __syncthreads();
  int k = tid & 31, grp = tid >> 5;
  int n = blockIdx.x*8 + grp;
  const float inv_avg = 1.0f/16.0f;
  float a[16];
  float4* Arow = (float4*)(Abuf + ((size_t)n*KDIM + k)*NSHD);
  #pragma unroll
  for (int q=0;q<4;q++){
    float4 t = Arow[q];
    a[q*4+0]=t.x*inv_avg; a[q*4+1]=t.y*inv_avg;
    a[q*4+2]=t.z*inv_avg; a[q*4+3]=t.w*inv_avg;
  }
  float g3[16];
  #pragma unroll
  for (int i=0;i<16;i++) g3[i]=0.f;
  int pid = 0;
  #pragma unroll
  for (int j=0;j<16;j++){
    #pragma unroll
    for (int l=j;l<16;l++){
      float pa = a[j]*a[l];
      const float4* s3r = (const float4*)(sS3 + pid*16);
      float4 c0 = s3r[0], c1 = s3r[1], c2 = s3r[2], c3 = s3r[3];
      g3[0] =fmaf(c0.x,pa,g3[0]);  g3[1] =fmaf(c0.y,pa,g3[1]);
      g3[2] =fmaf(c0.z,pa,g3[2]);  g3[3] =fmaf(c0.w,pa,g3[3]);
      g3[4] =fmaf(c1.x,pa,g3[4]);  g3[5] =fmaf(c1.y,pa,g3[5]);
      g3[6] =fmaf(c1.z,pa,g3[6]);  g3[7] =fmaf(c1.w,pa,g3[7]);
      g3[8] =fmaf(c2.x,pa,g3[8]);  g3[9] =fmaf(c2.y,pa,g3[9]);
      g3[10]=fmaf(c2.z,pa,g3[10]); g3[11]=fmaf(c2.w,pa,g3[11]);
      g3[12]=fmaf(c3.x,pa,g3[12]); g3[13]=fmaf(c3.y,pa,g3[13]);
      g3[14]=fmaf(c3.z,pa,g3[14]); g3[15]=fmaf(c3.w,pa,g3[15]);
      pid++;
    }
  }
  float c1k=c123[k], c2k=c123[KDIM+k], c3k=c123[2*KDIM+k];
  float B2=0.f, B3=0.f;
  float o0=0.f,o1=0.f,o2=0.f;
  #pragma unroll
  for (int i=0;i<16;i++){
    float g2i=0.f;
    #pragma unroll
    for (int j=0;j<16;j++) g2i = fmaf(sU2[j*16+i], a[j], g2i);
    B2 += a[i]*g2i;
    B3 += a[i]*g3[i];
    float o = (c2k*g2i + c3k*g3[i])*inv_avg;
    if (i==0) o += c1k*inv_avg;
    int ph = i&3;
    if (ph==0) o0=o;
    else if (ph==1) o1=o;
    else if (ph==2) o2=o;
    else Arow[i>>2] = make_float4(o0,o1,o2,o);
  }
  B2 *= 0.5f; B3 *= (1.0f/3.0f);
  float contrib = a[0]*c1k + B2*c2k + B3*c3k + xbuf[(size_t)n*KDIM+k]*Wread[k];
  #pragma unroll
  for (int off=1; off<32; off<<=1) contrib += __shfl_xor(contrib, off, 64);
  if (k==0) econ[n] = contrib;
}

// ---------------------------------------------------------------- energy reduce
__global__ void reduce_e_kernel(const float* __restrict__ econ,
                                const float* __restrict__ e0con,
                                const int* __restrict__ batch,
                                float* __restrict__ out_e){
  __shared__ float part[NGRAPH];
  int tid = threadIdx.x;
  if (tid < NGRAPH) part[tid]=0.f;
  __syncthreads();
  int n = blockIdx.x*256 + tid;
  float v = econ[n] + e0con[n];
  atomicAdd(&part[batch[n]], v);
  __syncthreads();
  if (tid < NGRAPH) atomicAdd(&out_e[tid], part[tid]);
}

// ---------------------------------------------------------------- edge backward (thread-per-edge, LUT)
// NO atomics: stores per-edge gradient vector to SoA buffers (coalesced).
__global__ void __launch_bounds__(256) edge_bwd_kernel(
    const int* __restrict__ sndbuf, const int* __restrict__ rcvbuf,
    const float4* __restrict__ vbuf4, const float* __restrict__ ybuf,
    const float* __restrict__ lut, const float* __restrict__ gA,
    float* __restrict__ gvx_o, float* __restrict__ gvy_o, float* __restrict__ gvz_o){
  int p = blockIdx.x*256 + threadIdx.x;
  int snd = sndbuf[p], rcv = rcvbuf[p];
  float4 v4 = vbuf4[p];
  float vx=v4.x, vy=v4.y, vz=v4.z, r=v4.w;
  float invr = 1.0f/r;
  float ux=vx*invr, uy=vy*invr, uz=vz*invr;
  float u = r*INVR_MAX;
  float t = fminf(u,1.0f)*(float)LUTN;
  int gg = min((int)t, LUTN-1);
  float w = t - (float)gg;
  const float* rowA = lut + (size_t)gg*64;
  float s0,s1,s2,s3,s4,s5,s6,s7,s8,s9,s10,s11,s12,s13,s14,s15;
  compute_sh16(ux,uy,uz,
               s0,s1,s2,s3,s4,s5,s6,s7,s8,s9,s10,s11,s12,s13,s14,s15);
  const float4* ga4 = (const float4*)(gA + (size_t)rcv*512);
  const float4* y4  = (const float4*)(ybuf + (size_t)snd*KDIM);
  float G0=0.f,G1=0.f,G2=0.f,G3v=0.f,G4=0.f,G5=0.f,G6=0.f,G7=0.f;
  float G8=0.f,G9=0.f,G10=0.f,G11=0.f,G12=0.f,G13=0.f,G14=0.f,G15=0.f;
  float grad_r = 0.f;
  #pragma unroll
  for (int k4=0;k4<8;k4++){
    float4 r0 = *(const float4*)(rowA + k4*4);
    float4 r1 = *(const float4*)(rowA + 64 + k4*4);
    float4 d0 = *(const float4*)(rowA + 32 + k4*4);
    float4 d1 = *(const float4*)(rowA + 96 + k4*4);
    float rwv0 = r0.x+(r1.x-r0.x)*w, rwv1 = r0.y+(r1.y-r0.y)*w;
    float rwv2 = r0.z+(r1.z-r0.z)*w, rwv3 = r0.w+(r1.w-r0.w)*w;
    float dr0 = d0.x+(d1.x-d0.x)*w, dr1 = d0.y+(d1.y-d0.y)*w;
    float dr2 = d0.z+(d1.z-d0.z)*w, dr3 = d0.w+(d1.w-d0.w)*w;
    float4 yv = y4[k4];
    #pragma unroll
    for (int q=0;q<4;q++){
      int k = k4*4+q;
      float yk  = (q==0)?yv.x:((q==1)?yv.y:((q==2)?yv.z:yv.w));
      float rwq = (q==0)?rwv0:((q==1)?rwv1:((q==2)?rwv2:rwv3));
      float drq = (q==0)?dr0:((q==1)?dr1:((q==2)?dr2:dr3));
      float xsk = yk*rwq;
      float4 t0 = ga4[k*4+0];
      float4 t1 = ga4[k*4+1];
      float4 t2 = ga4[k*4+2];
      float4 t3 = ga4[k*4+3];
      float gxs = t0.x*s0+t0.y*s1+t0.z*s2+t0.w*s3
                + t1.x*s4+t1.y*s5+t1.z*s6+t1.w*s7
                + t2.x*s8+t2.y*s9+t2.z*s10+t2.w*s11
                + t3.x*s12+t3.y*s13+t3.z*s14+t3.w*s15;
      G0  = fmaf(t0.x,xsk,G0);  G1  = fmaf(t0.y,xsk,G1);
      G2  = fmaf(t0.z,xsk,G2);  G3v = fmaf(t0.w,xsk,G3v);
      G4  = fmaf(t1.x,xsk,G4);  G5  = fmaf(t1.y,xsk,G5);
      G6  = fmaf(t1.z,xsk,G6);  G7  = fmaf(t1.w,xsk,G7);
      G8  = fmaf(t2.x,xsk,G8);  G9  = fmaf(t2.y,xsk,G9);
      G10 = fmaf(t2.z,xsk,G10); G11 = fmaf(t2.w,xsk,G11);
      G12 = fmaf(t3.x,xsk,G12); G13 = fmaf(t3.y,xsk,G13);
      G14 = fmaf(t3.z,xsk,G14); G15 = fmaf(t3.w,xsk,G15);
      grad_r += gxs*yk*drq;
    }
  }
  float x_=ux, y_=uy, z_=uz;
  float x2=x_*x_, y2=y_*y_, z2=z_*z_;
  float gux = 0.48860251f*G3v
            + 1.09254843f*(y_*G4 + z_*G7)
            + 1.09254844f*x_*G8
            + 3.54026154f*x_*y_*G9
            + 2.89061144f*y_*z_*G10
            + 0.45704579f*(5.0f*z2-1.0f)*G13
            + 2.89061144f*x_*z_*G14
            + 1.77013077f*(x2-y2)*G15;
  float guy = 0.48860251f*G1
            + 1.09254843f*(x_*G4 + z_*G5)
            - 1.09254844f*y_*G8
            + 1.77013077f*(x2-y2)*G9
            + 2.89061144f*x_*z_*G10
            + 0.45704579f*(5.0f*z2-1.0f)*G11
            - 2.89061144f*y_*z_*G14
            - 3.54026154f*x_*y_*G15;
  float guz = 0.48860251f*G2
            + 1.09254843f*(y_*G5 + x_*G7)
            + 1.89234942f*z_*G6
            + 2.89061144f*x_*y_*G10
            + 4.5704579f*y_*z_*G11
            + 0.37317633f*(15.0f*z2-3.0f)*G12
            + 4.5704579f*x_*z_*G13
            + 1.44530572f*(x2-y2)*G14;
  float dotg = gux*x_ + guy*y_ + guz*z_;
  gvx_o[p] = grad_r*x_ + (gux - dotg*x_)*invr;
  gvy_o[p] = grad_r*y_ + (guy - dotg*y_)*invr;
  gvz_o[p] = grad_r*z_ + (guz - dotg*z_)*invr;
}

// ---------------------------------------------------------------- force assembly
__global__ void force_kernel(const int* __restrict__ row_start,
                             const int* __restrict__ row2_start,
                             const int* __restrict__ elist2,
                             const float* __restrict__ gvx, const float* __restrict__ gvy,
                             const float* __restrict__ gvz, float* __restrict__ F){
  int n = blockIdx.x*256 + threadIdx.x;
  float fx=0.f, fy=0.f, fz=0.f;
  int rs=row_start[n], re=row_start[n+1];
  for (int p=rs; p<re; ++p){
    fx -= gvx[p]; fy -= gvy[p]; fz -= gvz[p];
  }
  int s2=row2_start[n], e2=row2_start[n+1];
  for (int q=s2; q<e2; ++q){
    int p = elist2[q];
    fx += gvx[p]; fy += gvy[p]; fz += gvz[p];
  }
  F[n*3+0]=fx; F[n*3+1]=fy; F[n*3+2]=fz;
}

extern "C" void kernel_launch(void* const* d_in, const int* in_sizes, int n_in,
                              void* d_out, int out_size, void* d_ws, size_t ws_size,
                              hipStream_t stream){
  const float* positions       = (const float*)d_in[0];
  const float* node_attrs      = (const float*)d_in[1];
  const int*   edge_index      = (const int*)  d_in[2];
  const float* shifts          = (const float*)d_in[3];
  const int*   batch           = (const int*)  d_in[4];
  const float* atomic_energies = (const float*)d_in[6];
  const float* W_embed         = (const float*)d_in[7];
  const float* W_up            = (const float*)d_in[8];
  const float* W_r1            = (const float*)d_in[9];
  const float* b_r1            = (const float*)d_in[10];
  const float* W_r2            = (const float*)d_in[11];
  const float* U2              = (const float*)d_in[12];
  const float* U3              = (const float*)d_in[13];
  const float* Wp1             = (const float*)d_in[14];
  const float* Wp2             = (const float*)d_in[15];
  const float* Wp3             = (const float*)d_in[16];
  const float* W_read          = (const float*)d_in[17];
  float* out = (float*)d_out;

  float* Abuf  = (float*)d_ws;                        // N*512 (A, then gA in place)
  float* xbuf  = Abuf  + (size_t)NNODES*KDIM*NSHD;    // N*32
  float* ybuf  = xbuf  + (size_t)NNODES*KDIM;         // N*32
  float* lut   = ybuf  + (size_t)NNODES*KDIM;         // 2050*64 = 131200
  float* S3    = lut   + (size_t)2050*64;             // 136*16 -> pad 2304
  float* U2s   = S3    + 2304;                        // 256
  float* c123  = U2s   + 256;                         // 96 -> pad 128
  float* econ  = c123  + 128;                         // N
  float* e0con = econ  + NNODES;                      // N
  float4* vbuf4 = (float4*)(e0con + NNODES);          // E float4 (16B aligned)
  float* gvx   = (float*)(vbuf4 + (size_t)NEDGES);    // E
  float* gvy   = gvx + NEDGES;                        // E
  float* gvz   = gvy + NEDGES;                        // E
  int* sndbuf  = (int*)(gvz + NEDGES);                // E
  int* rcvbuf  = sndbuf + NEDGES;                     // E
  int* pos_of_e = rcvbuf + NEDGES;                    // E
  int* cnt       = pos_of_e + NEDGES;                 // N  (cnt & cnt2 adjacent: 1 memset)
  int* cnt2      = cnt + NNODES;                      // N
  int* row_start = cnt2 + NNODES;                     // N+1 (pad 64)
  int* row2      = row_start + NNODES + 64;           // N+1 (pad 64)
  int* woff      = row2 + NNODES + 64;                // N
  int* woff2     = woff + NNODES;                     // N
  int* elist2    = woff2 + NNODES;                    // E

  hipMemsetAsync(out, 0, sizeof(float)*NGRAPH, stream);
  hipMemsetAsync(cnt, 0, sizeof(int)*2*NNODES, stream);

  prep_kernel<<<1,256,0,stream>>>(U2,U3,Wp1,Wp2,Wp3,W_read,S3,U2s,c123);
  lut_kernel<<<(LUTN+1+255)/256,256,0,stream>>>(W_r1,b_r1,W_r2,lut);
  count_kernel<<<NEDGES/256,256,0,stream>>>(edge_index, cnt, cnt2);
  scan2_kernel<<<2,1024,0,stream>>>(cnt, row_start, woff, cnt2, row2, woff2);
  scatter_geom_kernel<<<NEDGES/256,256,0,stream>>>(edge_index, shifts, positions,
                                                   woff, pos_of_e, vbuf4, sndbuf, rcvbuf);
  csr2_scatter_kernel<<<NEDGES/256,256,0,stream>>>(edge_index, pos_of_e, woff2, elist2);
  node_embed_kernel<<<NNODES/4,256,0,stream>>>(node_attrs,W_embed,W_up,atomic_energies,
                                               xbuf,ybuf,e0con);
  node_accA_kernel<<<NNODES/4,256,0,stream>>>(row_start,vbuf4,sndbuf,ybuf,lut,Abuf);
  node_b_kernel<<<NNODES/8,256,0,stream>>>(Abuf,xbuf,S3,U2s,c123,W_read,econ);
  reduce_e_kernel<<<NNODES/256,256,0,stream>>>(econ,e0con,batch,out);
  edge_bwd_kernel<<<NEDGES/256,256,0,stream>>>(sndbuf,rcvbuf,vbuf4,ybuf,lut,Abuf,
                                               gvx,gvy,gvz);
  force_kernel<<<NNODES/256,256,0,stream>>>(row_start,row2,elist2,gvx,gvy,gvz,out+NGRAPH);
}

// Round 13
// 530.738 us; speedup vs baseline: 6.0566x; 1.3428x over previous
//
#include <hip/hip_runtime.h>
#include <math.h>

#define NNODES 32768
#define NEDGES 524288
#define KDIM 32
#define NSHD 16
#define NB 8
#define NHID 64
#define NGRAPH 16
#define NELEM 10
#define RMAXF 5.0f
#define INVR_MAX 0.2f
#define PI_F 3.14159265358979f
#define CBES 0.632455532033676f   /* sqrt(2/R_MAX) */
#define LUTN 2048

typedef __attribute__((ext_vector_type(8))) short bf16x8;
typedef __attribute__((ext_vector_type(4))) float floatx4;

__device__ __forceinline__ unsigned short f2bf(float x){
  unsigned u = __float_as_uint(x);
  unsigned r = (u + 0x7FFFu + ((u>>16)&1u)) >> 16;
  return (unsigned short)r;
}

// 16 named outputs: keeps SH values in VGPRs (array form triggered
// PromoteAlloca -> LDS with 32-way bank conflicts, R5 post-mortem).
__device__ __forceinline__ void compute_sh16(float x, float y, float z,
    float& s0, float& s1, float& s2, float& s3,
    float& s4, float& s5, float& s6, float& s7,
    float& s8, float& s9, float& s10, float& s11,
    float& s12, float& s13, float& s14, float& s15){
  float x2=x*x, y2=y*y, z2=z*z;
  s0=0.28209479f;
  s1=0.48860251f*y;
  s2=0.48860251f*z;
  s3=0.48860251f*x;
  s4=1.09254843f*x*y;
  s5=1.09254843f*y*z;
  s6=0.31539157f*(3.0f*z2-1.0f);
  s7=1.09254843f*x*z;
  s8=0.54627422f*(x2-y2);
  s9=0.59004359f*y*(3.0f*x2-y2);
  s10=2.89061144f*x*y*z;
  s11=0.45704579f*y*(5.0f*z2-1.0f);
  s12=0.37317633f*z*(5.0f*z2-3.0f);
  s13=0.45704579f*x*(5.0f*z2-1.0f);
  s14=1.44530572f*z*(x2-y2);
  s15=0.59004359f*x*(x2-3.0f*y2);
}

// ---------------------------------------------------------------- prep
// Builds MFMA A-fragments for the pair contraction.
// Pair groups g=0..23 (constant J, consecutive l = Lb..Lb+7, zero-padded l>15):
//   g<16: J=g>>1, Lb=(g&1)? J+8 : J ;  g>=16: J=g-8, Lb=J.
// Chunks c=0..5 cover groups g=c*4+q (q=lane quad); chunk 6 = U2s (g2 GEMM).
// S3frag[c*512 + q*128 + i*8 + jj] = bf16 coeff for A[m=i][k=q*8+jj] of chunk c.
__global__ void prep_kernel(const float* __restrict__ U2, const float* __restrict__ U3,
                            const float* __restrict__ Wp1, const float* __restrict__ Wp2,
                            const float* __restrict__ Wp3, const float* __restrict__ Wread,
                            unsigned short* __restrict__ S3frag, int* __restrict__ gtab,
                            float* __restrict__ c123){
  __shared__ float sU2[256];
  int t = threadIdx.x;
  sU2[t] = U2[(t>>4)*16+(t&15)] + U2[(t&15)*16+(t>>4)];
  __syncthreads();
  if (t < 24){
    int J, Lb;
    if (t < 16){ J = t>>1; Lb = (t&1) ? J+8 : J; }
    else { J = t-8; Lb = J; }
    gtab[t] = (J<<8)|Lb;
  }
  for (int v=t; v<3584; v+=256){
    int c = v>>9, rem = v&511;
    int q = rem>>7, i = (rem>>3)&15, jj = rem&7;
    float val = 0.f;
    if (c < 6){
      int g = c*4+q;
      int J, Lb;
      if (g < 16){ J = g>>1; Lb = (g&1) ? J+8 : J; }
      else { J = g-8; Lb = J; }
      int l = Lb+jj;
      if (l <= 15){
        int j = J;
        if (j==l) val = U3[i*256+j*16+j]+U3[j*256+i*16+j]+U3[j*256+j*16+i];
        else      val = U3[i*256+j*16+l]+U3[j*256+i*16+l]+U3[j*256+l*16+i]
                      + U3[i*256+l*16+j]+U3[l*256+i*16+j]+U3[l*256+j*16+i];
      }
    } else {
      int s = q*8+jj;
      if (s < 16) val = sU2[s*16+i];
    }
    S3frag[v] = f2bf(val);
  }
  if (t < 96){
    int which = t >> 5, k = t & 31;
    const float* Wp = (which==0)?Wp1:((which==1)?Wp2:Wp3);
    float s = 0.f;
    for (int q=0;q<KDIM;q++) s += Wp[k*KDIM+q]*Wread[q];
    c123[t] = s;
  }
}

// ---------------------------------------------------------------- radial LUT
__global__ void lut_kernel(const float* __restrict__ W_r1, const float* __restrict__ b_r1,
                           const float* __restrict__ W_r2, float* __restrict__ lut){
  int g = blockIdx.x*256 + threadIdx.x;
  if (g > LUTN) return;
  float r = fmaxf(5.0f*(float)g/(float)LUTN, 1e-9f);
  float invr = 1.0f/r;
  float u = r*INVR_MAX;
  float cut = 0.f, dcdr = 0.f;
  if (u < 1.0f){
    float u2=u*u, u3=u2*u, u6=u3*u3;
    cut = 1.0f - 28.0f*u6 + 48.0f*u6*u - 21.0f*u6*u2;
    float u4=u2*u2, om=1.0f-u;
    dcdr = -168.0f*u4*u*om*om*INVR_MAX;
  }
  float b[NB], db[NB];
  #pragma unroll
  for (int q=0;q<NB;q++){
    float nn = (float)(q+1);
    float ang = PI_F*nn*u;
    float S = sinf(ang), C = cosf(ang);
    b[q]  = CBES*S*invr*cut;
    db[q] = CBES*invr*((PI_F*nn*INVR_MAX)*C - S*invr)*cut + CBES*S*invr*dcdr;
  }
  float Rw[KDIM], dRw[KDIM];
  #pragma unroll
  for (int k=0;k<KDIM;k++){ Rw[k]=0.f; dRw[k]=0.f; }
  for (int m=0;m<NHID;m++){
    float h = b_r1[m], dh = 0.f;
    #pragma unroll
    for (int q=0;q<NB;q++){ h += b[q]*W_r1[q*NHID+m]; dh += db[q]*W_r1[q*NHID+m]; }
    float sg = 1.0f/(1.0f+expf(-h));
    float s  = h*sg;
    float sp = sg*(1.0f + h*(1.0f-sg));
    float f  = sp*dh;
    #pragma unroll
    for (int k=0;k<KDIM;k++){
      Rw[k]  += s*W_r2[m*KDIM+k];
      dRw[k] += f*W_r2[m*KDIM+k];
    }
  }
  #pragma unroll
  for (int k=0;k<KDIM;k++){
    lut[(size_t)g*64 + k]      = Rw[k];
    lut[(size_t)g*64 + 32 + k] = dRw[k];
  }
}

// ---------------------------------------------------------------- CSR: count both sides in one pass
__global__ void count_kernel(const int* __restrict__ eidx,
                             int* __restrict__ cnt, int* __restrict__ cnt2){
  int e = blockIdx.x*256 + threadIdx.x;
  atomicAdd(&cnt[eidx[NEDGES + e]], 1);
  atomicAdd(&cnt2[eidx[e]], 1);
}

__global__ void scan2_kernel(const int* __restrict__ cntA, int* __restrict__ rowA,
                             int* __restrict__ woffA,
                             const int* __restrict__ cntB, int* __restrict__ rowB,
                             int* __restrict__ woffB){
  const int* cnt = blockIdx.x ? cntB : cntA;
  int* row_start = blockIdx.x ? rowB : rowA;
  int* woff      = blockIdx.x ? woffB : woffA;
  __shared__ int part[1024];
  int t = threadIdx.x;
  int base_idx = t*32;
  int local[32];
  int s = 0;
  #pragma unroll
  for (int j=0;j<32;j++){
    int c = cnt[base_idx+j];
    local[j] = s;
    s += c;
  }
  part[t] = s;
  __syncthreads();
  for (int off=1; off<1024; off<<=1){
    int v = (t>=off) ? part[t-off] : 0;
    __syncthreads();
    part[t] += v;
    __syncthreads();
  }
  int base = (t==0) ? 0 : part[t-1];
  #pragma unroll
  for (int j=0;j<32;j++){
    int v = base + local[j];
    row_start[base_idx+j] = v;
    woff[base_idx+j] = v;
  }
  if (t==1023) row_start[NNODES] = part[1023];
}

// ---------------------------------------------------------------- scatter + edge geometry (fused)
__global__ void scatter_geom_kernel(const int* __restrict__ eidx,
                                    const float* __restrict__ shifts,
                                    const float* __restrict__ pos,
                                    int* __restrict__ woff, int* __restrict__ pos_of_e,
                                    float4* __restrict__ vbuf4,
                                    int* __restrict__ sndbuf, int* __restrict__ rcvbuf){
  int e = blockIdx.x*256 + threadIdx.x;
  int snd = eidx[e], rcv = eidx[NEDGES + e];
  int p = atomicAdd(&woff[rcv], 1);
  float vx = pos[rcv*3+0] - pos[snd*3+0] + shifts[(size_t)e*3+0];
  float vy = pos[rcv*3+1] - pos[snd*3+1] + shifts[(size_t)e*3+1];
  float vz = pos[rcv*3+2] - pos[snd*3+2] + shifts[(size_t)e*3+2];
  float r = sqrtf(vx*vx+vy*vy+vz*vz + 1e-18f);
  vbuf4[p] = make_float4(vx,vy,vz,r);
  sndbuf[p] = snd;
  rcvbuf[p] = rcv;
  pos_of_e[e] = p;
}

__global__ void csr2_scatter_kernel(const int* __restrict__ eidx,
                                    const int* __restrict__ pos_of_e,
                                    int* __restrict__ woff2, int* __restrict__ elist2){
  int e = blockIdx.x*256 + threadIdx.x;
  int s = eidx[e];
  int slot = atomicAdd(&woff2[s], 1);
  elist2[slot] = pos_of_e[e];
}

// ---------------------------------------------------------------- node embed
__global__ void node_embed_kernel(const float* __restrict__ attrs,
                                  const float* __restrict__ W_embed,
                                  const float* __restrict__ W_up,
                                  const float* __restrict__ ae,
                                  float* __restrict__ xbuf, float* __restrict__ ybuf,
                                  float* __restrict__ e0con){
  int gtid = blockIdx.x*256 + threadIdx.x;
  int n = gtid >> 6;
  int lane = threadIdx.x & 63;
  int k = lane & 31;
  float xv = 0.f;
  #pragma unroll
  for (int e=0;e<NELEM;e++) xv += attrs[n*NELEM+e]*W_embed[e*KDIM+k];
  float yv = 0.f;
  #pragma unroll 8
  for (int k2=0;k2<KDIM;k2++) yv += __shfl(xv, k2, 64) * W_up[k2*KDIM+k];
  if (lane < 32){
    xbuf[n*KDIM+k]=xv;
    ybuf[n*KDIM+k]=yv;
  }
  if (lane == 0){
    float s=0.f;
    #pragma unroll
    for (int e=0;e<NELEM;e++) s += attrs[n*NELEM+e]*ae[e];
    e0con[n] = s;
  }
}

// ---------------------------------------------------------------- A accumulation
__global__ void __launch_bounds__(256) node_accA_kernel(
    const int* __restrict__ row_start, const float4* __restrict__ vbuf4,
    const int* __restrict__ sndbuf, const float* __restrict__ ybuf,
    const float* __restrict__ lut, float* __restrict__ A){
  int tid = threadIdx.x;
  int wl = tid>>6, lane = tid&63;
  int n = blockIdx.x*4 + wl;
  int k2 = lane>>1, ihalf = lane&1;
  float a0=0.f,a1=0.f,a2=0.f,a3=0.f,a4=0.f,a5=0.f,a6=0.f,a7=0.f;
  int rs=row_start[n], re=row_start[n+1];
  for (int p=rs; p<re; ++p){
    float4 v4 = vbuf4[p];
    int snd = sndbuf[p];
    float r = v4.w;
    float invr = 1.0f/r;
    float u = r*INVR_MAX;
    float t = fminf(u,1.0f)*(float)LUTN;
    int gg = min((int)t, LUTN-1);
    float w = t - (float)gg;
    const float* rowA = lut + (size_t)gg*64;
    float rw0 = rowA[k2], rw1 = rowA[64+k2];
    float rw = rw0 + (rw1-rw0)*w;
    float y = ybuf[(size_t)snd*KDIM + k2];
    float xs = y*rw;
    float s0,s1,s2,s3,s4,s5,s6,s7,s8,s9,s10,s11,s12,s13,s14,s15;
    compute_sh16(v4.x*invr, v4.y*invr, v4.z*invr,
                 s0,s1,s2,s3,s4,s5,s6,s7,s8,s9,s10,s11,s12,s13,s14,s15);
    float e0 = ihalf ? s8  : s0;
    float e1 = ihalf ? s9  : s1;
    float e2 = ihalf ? s10 : s2;
    float e3 = ihalf ? s11 : s3;
    float e4 = ihalf ? s12 : s4;
    float e5 = ihalf ? s13 : s5;
    float e6 = ihalf ? s14 : s6;
    float e7 = ihalf ? s15 : s7;
    a0 = fmaf(xs, e0, a0);
    a1 = fmaf(xs, e1, a1);
    a2 = fmaf(xs, e2, a2);
    a3 = fmaf(xs, e3, a3);
    a4 = fmaf(xs, e4, a4);
    a5 = fmaf(xs, e5, a5);
    a6 = fmaf(xs, e6, a6);
    a7 = fmaf(xs, e7, a7);
  }
  float4* Ao = (float4*)(A + (size_t)n*512 + lane*8);
  Ao[0] = make_float4(a0,a1,a2,a3);
  Ao[1] = make_float4(a4,a5,a6,a7);
}

// ---------------------------------------------------------------- node B-ops (MFMA)
// wave = 1 node. G3[i][k] & G2[i][k] via mfma_f32_16x16x32_bf16:
//   A = S3frag chunks (constant, loaded once), B = pa pairs built per-lane from
//   LDS-staged a-row (stride 17). C/D: col=lane&15 (k_local), row=quad*4+reg (i).
// 14 MFMA/node replace ~2700 VALU FMA + 400 LDS broadcasts of the old kernel.
__global__ void __launch_bounds__(256) node_b_kernel(
    float* Abuf, const float* __restrict__ xbuf,
    const unsigned short* __restrict__ S3frag, const int* __restrict__ gtab,
    const float* __restrict__ c123, const float* __restrict__ Wread,
    float* __restrict__ econ){
  __shared__ float a_lds[4*544];
  int tid = threadIdx.x;
  int wl = tid>>6, lane = tid&63;
  int n = blockIdx.x*4 + wl;
  float* aL = a_lds + wl*544;
  const float inv_avg = 1.0f/16.0f;
  // stage a = Abuf[n]/16 into aL[k*17 + i]  (stride 17 breaks bank aliasing)
  {
    const float4* src = (const float4*)(Abuf + (size_t)n*512 + lane*8);
    float4 v0 = src[0], v1 = src[1];
    int k = lane>>1, ih = lane&1;
    float* dst = aL + k*17 + ih*8;
    dst[0]=v0.x*inv_avg; dst[1]=v0.y*inv_avg; dst[2]=v0.z*inv_avg; dst[3]=v0.w*inv_avg;
    dst[4]=v1.x*inv_avg; dst[5]=v1.y*inv_avg; dst[6]=v1.z*inv_avg; dst[7]=v1.w*inv_avg;
  }
  // constant A-fragments (bf16), one b128 each, L2-hot
  bf16x8 af0 = *(const bf16x8*)(S3frag + 0*512 + lane*8);
  bf16x8 af1 = *(const bf16x8*)(S3frag + 1*512 + lane*8);
  bf16x8 af2 = *(const bf16x8*)(S3frag + 2*512 + lane*8);
  bf16x8 af3 = *(const bf16x8*)(S3frag + 3*512 + lane*8);
  bf16x8 af4 = *(const bf16x8*)(S3frag + 4*512 + lane*8);
  bf16x8 af5 = *(const bf16x8*)(S3frag + 5*512 + lane*8);
  bf16x8 af6 = *(const bf16x8*)(S3frag + 6*512 + lane*8);
  int q = lane>>4, cc = lane&15;
  int J0,Lb0,J1,Lb1,J2,Lb2,J3,Lb3,J4,Lb4,J5,Lb5;
  { int gv=gtab[0*4+q]; J0=gv>>8; Lb0=gv&255; }
  { int gv=gtab[1*4+q]; J1=gv>>8; Lb1=gv&255; }
  { int gv=gtab[2*4+q]; J2=gv>>8; Lb2=gv&255; }
  { int gv=gtab[3*4+q]; J3=gv>>8; Lb3=gv&255; }
  { int gv=gtab[4*4+q]; J4=gv>>8; Lb4=gv&255; }
  { int gv=gtab[5*4+q]; J5=gv>>8; Lb5=gv&255; }
  __syncthreads();
  float csum = 0.f;
  #pragma unroll 1
  for (int t=0; t<2; t++){
    int kk = t*16 + cc;
    const float* ak = aL + kk*17;
    floatx4 c3acc = {0.f,0.f,0.f,0.f};
    floatx4 c2acc = {0.f,0.f,0.f,0.f};
    #define PA_CHUNK(AF, J, LB)                                        \
    {                                                                  \
      float aJ = ak[J];                                                \
      bf16x8 bf;                                                       \
      _Pragma("unroll")                                                \
      for (int jj=0;jj<8;jj++){                                        \
        int l = LB+jj; l = (l>15)?15:l;                                \
        bf[jj] = (short)f2bf(aJ*ak[l]);                                \
      }                                                                \
      c3acc = __builtin_amdgcn_mfma_f32_16x16x32_bf16(AF, bf, c3acc, 0,0,0); \
    }
    PA_CHUNK(af0, J0, Lb0)
    PA_CHUNK(af1, J1, Lb1)
    PA_CHUNK(af2, J2, Lb2)
    PA_CHUNK(af3, J3, Lb3)
    PA_CHUNK(af4, J4, Lb4)
    PA_CHUNK(af5, J5, Lb5)
    #undef PA_CHUNK
    {
      bf16x8 bf;
      #pragma unroll
      for (int jj=0;jj<8;jj++){
        int s = q*8+jj;
        float v = (s<16) ? ak[s] : 0.f;
        bf[jj] = (short)f2bf(v);
      }
      c2acc = __builtin_amdgcn_mfma_f32_16x16x32_bf16(af6, bf, c2acc, 0,0,0);
    }
    // epilogue: lane holds (i = q*4+r, k = kk)
    float c1k=c123[kk], c2k=c123[KDIM+kk], c3k=c123[2*KDIM+kk];
    float pB2=0.f, pB3=0.f;
    float o0,o1,o2,o3;
    {
      float g30=c3acc[0], g31=c3acc[1], g32=c3acc[2], g33=c3acc[3];
      float g20=c2acc[0], g21=c2acc[1], g22=c2acc[2], g23=c2acc[3];
      float ai0=ak[q*4+0], ai1=ak[q*4+1], ai2=ak[q*4+2], ai3=ak[q*4+3];
      pB2 = ai0*g20 + ai1*g21 + ai2*g22 + ai3*g23;
      pB3 = ai0*g30 + ai1*g31 + ai2*g32 + ai3*g33;
      o0 = (c2k*g20 + c3k*g30)*inv_avg;
      o1 = (c2k*g21 + c3k*g31)*inv_avg;
      o2 = (c2k*g22 + c3k*g32)*inv_avg;
      o3 = (c2k*g23 + c3k*g33)*inv_avg;
    }
    if (q==0) o0 += c1k*inv_avg;
    *(float4*)(Abuf + (size_t)n*512 + kk*16 + q*4) = make_float4(o0,o1,o2,o3);
    pB2 += __shfl_xor(pB2, 16);
    pB2 += __shfl_xor(pB2, 32);
    pB3 += __shfl_xor(pB3, 16);
    pB3 += __shfl_xor(pB3, 32);
    float contrib = ak[0]*c1k + 0.5f*pB2*c2k + (1.0f/3.0f)*pB3*c3k
                  + xbuf[(size_t)n*KDIM+kk]*Wread[kk];
    csum += (q==0) ? contrib : 0.f;
  }
  csum += __shfl_xor(csum, 1);
  csum += __shfl_xor(csum, 2);
  csum += __shfl_xor(csum, 4);
  csum += __shfl_xor(csum, 8);
  csum += __shfl_xor(csum, 16);
  csum += __shfl_xor(csum, 32);
  if (lane == 0) econ[n] = csum;
}

// ---------------------------------------------------------------- energy reduce
__global__ void reduce_e_kernel(const float* __restrict__ econ,
                                const float* __restrict__ e0con,
                                const int* __restrict__ batch,
                                float* __restrict__ out_e){
  __shared__ float part[NGRAPH];
  int tid = threadIdx.x;
  if (tid < NGRAPH) part[tid]=0.f;
  __syncthreads();
  int n = blockIdx.x*256 + tid;
  float v = econ[n] + e0con[n];
  atomicAdd(&part[batch[n]], v);
  __syncthreads();
  if (tid < NGRAPH) atomicAdd(&out_e[tid], part[tid]);
}

// ---------------------------------------------------------------- edge backward (thread-per-edge, LUT)
__global__ void __launch_bounds__(256) edge_bwd_kernel(
    const int* __restrict__ sndbuf, const int* __restrict__ rcvbuf,
    const float4* __restrict__ vbuf4, const float* __restrict__ ybuf,
    const float* __restrict__ lut, const float* __restrict__ gA,
    float* __restrict__ gvx_o, float* __restrict__ gvy_o, float* __restrict__ gvz_o){
  int p = blockIdx.x*256 + threadIdx.x;
  int snd = sndbuf[p], rcv = rcvbuf[p];
  float4 v4 = vbuf4[p];
  float vx=v4.x, vy=v4.y, vz=v4.z, r=v4.w;
  float invr = 1.0f/r;
  float ux=vx*invr, uy=vy*invr, uz=vz*invr;
  float u = r*INVR_MAX;
  float t = fminf(u,1.0f)*(float)LUTN;
  int gg = min((int)t, LUTN-1);
  float w = t - (float)gg;
  const float* rowA = lut + (size_t)gg*64;
  float s0,s1,s2,s3,s4,s5,s6,s7,s8,s9,s10,s11,s12,s13,s14,s15;
  compute_sh16(ux,uy,uz,
               s0,s1,s2,s3,s4,s5,s6,s7,s8,s9,s10,s11,s12,s13,s14,s15);
  const float4* ga4 = (const float4*)(gA + (size_t)rcv*512);
  const float4* y4  = (const float4*)(ybuf + (size_t)snd*KDIM);
  float G0=0.f,G1=0.f,G2=0.f,G3v=0.f,G4=0.f,G5=0.f,G6=0.f,G7=0.f;
  float G8=0.f,G9=0.f,G10=0.f,G11=0.f,G12=0.f,G13=0.f,G14=0.f,G15=0.f;
  float grad_r = 0.f;
  #pragma unroll
  for (int k4=0;k4<8;k4++){
    float4 r0 = *(const float4*)(rowA + k4*4);
    float4 r1 = *(const float4*)(rowA + 64 + k4*4);
    float4 d0 = *(const float4*)(rowA + 32 + k4*4);
    float4 d1 = *(const float4*)(rowA + 96 + k4*4);
    float rwv0 = r0.x+(r1.x-r0.x)*w, rwv1 = r0.y+(r1.y-r0.y)*w;
    float rwv2 = r0.z+(r1.z-r0.z)*w, rwv3 = r0.w+(r1.w-r0.w)*w;
    float dr0 = d0.x+(d1.x-d0.x)*w, dr1 = d0.y+(d1.y-d0.y)*w;
    float dr2 = d0.z+(d1.z-d0.z)*w, dr3 = d0.w+(d1.w-d0.w)*w;
    float4 yv = y4[k4];
    #pragma unroll
    for (int q=0;q<4;q++){
      int k = k4*4+q;
      float yk  = (q==0)?yv.x:((q==1)?yv.y:((q==2)?yv.z:yv.w));
      float rwq = (q==0)?rwv0:((q==1)?rwv1:((q==2)?rwv2:rwv3));
      float drq = (q==0)?dr0:((q==1)?dr1:((q==2)?dr2:dr3));
      float xsk = yk*rwq;
      float4 t0 = ga4[k*4+0];
      float4 t1 = ga4[k*4+1];
      float4 t2 = ga4[k*4+2];
      float4 t3 = ga4[k*4+3];
      float gxs = t0.x*s0+t0.y*s1+t0.z*s2+t0.w*s3
                + t1.x*s4+t1.y*s5+t1.z*s6+t1.w*s7
                + t2.x*s8+t2.y*s9+t2.z*s10+t2.w*s11
                + t3.x*s12+t3.y*s13+t3.z*s14+t3.w*s15;
      G0  = fmaf(t0.x,xsk,G0);  G1  = fmaf(t0.y,xsk,G1);
      G2  = fmaf(t0.z,xsk,G2);  G3v = fmaf(t0.w,xsk,G3v);
      G4  = fmaf(t1.x,xsk,G4);  G5  = fmaf(t1.y,xsk,G5);
      G6  = fmaf(t1.z,xsk,G6);  G7  = fmaf(t1.w,xsk,G7);
      G8  = fmaf(t2.x,xsk,G8);  G9  = fmaf(t2.y,xsk,G9);
      G10 = fmaf(t2.z,xsk,G10); G11 = fmaf(t2.w,xsk,G11);
      G12 = fmaf(t3.x,xsk,G12); G13 = fmaf(t3.y,xsk,G13);
      G14 = fmaf(t3.z,xsk,G14); G15 = fmaf(t3.w,xsk,G15);
      grad_r += gxs*yk*drq;
    }
  }
  float x_=ux, y_=uy, z_=uz;
  float x2=x_*x_, y2=y_*y_, z2=z_*z_;
  float gux = 0.48860251f*G3v
            + 1.09254843f*(y_*G4 + z_*G7)
            + 1.09254844f*x_*G8
            + 3.54026154f*x_*y_*G9
            + 2.89061144f*y_*z_*G10
            + 0.45704579f*(5.0f*z2-1.0f)*G13
            + 2.89061144f*x_*z_*G14
            + 1.77013077f*(x2-y2)*G15;
  float guy = 0.48860251f*G1
            + 1.09254843f*(x_*G4 + z_*G5)
            - 1.09254844f*y_*G8
            + 1.77013077f*(x2-y2)*G9
            + 2.89061144f*x_*z_*G10
            + 0.45704579f*(5.0f*z2-1.0f)*G11
            - 2.89061144f*y_*z_*G14
            - 3.54026154f*x_*y_*G15;
  float guz = 0.48860251f*G2
            + 1.09254843f*(y_*G5 + x_*G7)
            + 1.89234942f*z_*G6
            + 2.89061144f*x_*y_*G10
            + 4.5704579f*y_*z_*G11
            + 0.37317633f*(15.0f*z2-3.0f)*G12
            + 4.5704579f*x_*z_*G13
            + 1.44530572f*(x2-y2)*G14;
  float dotg = gux*x_ + guy*y_ + guz*z_;
  gvx_o[p] = grad_r*x_ + (gux - dotg*x_)*invr;
  gvy_o[p] = grad_r*y_ + (guy - dotg*y_)*invr;
  gvz_o[p] = grad_r*z_ + (guz - dotg*z_)*invr;
}

// ---------------------------------------------------------------- force assembly
__global__ void force_kernel(const int* __restrict__ row_start,
                             const int* __restrict__ row2_start,
                             const int* __restrict__ elist2,
                             const float* __restrict__ gvx, const float* __restrict__ gvy,
                             const float* __restrict__ gvz, float* __restrict__ F){
  int n = blockIdx.x*256 + threadIdx.x;
  float fx=0.f, fy=0.f, fz=0.f;
  int rs=row_start[n], re=row_start[n+1];
  for (int p=rs; p<re; ++p){
    fx -= gvx[p]; fy -= gvy[p]; fz -= gvz[p];
  }
  int s2=row2_start[n], e2=row2_start[n+1];
  for (int q=s2; q<e2; ++q){
    int p = elist2[q];
    fx += gvx[p]; fy += gvy[p]; fz += gvz[p];
  }
  F[n*3+0]=fx; F[n*3+1]=fy; F[n*3+2]=fz;
}

extern "C" void kernel_launch(void* const* d_in, const int* in_sizes, int n_in,
                              void* d_out, int out_size, void* d_ws, size_t ws_size,
                              hipStream_t stream){
  const float* positions       = (const float*)d_in[0];
  const float* node_attrs      = (const float*)d_in[1];
  const int*   edge_index      = (const int*)  d_in[2];
  const float* shifts          = (const float*)d_in[3];
  const int*   batch           = (const int*)  d_in[4];
  const float* atomic_energies = (const float*)d_in[6];
  const float* W_embed         = (const float*)d_in[7];
  const float* W_up            = (const float*)d_in[8];
  const float* W_r1            = (const float*)d_in[9];
  const float* b_r1            = (const float*)d_in[10];
  const float* W_r2            = (const float*)d_in[11];
  const float* U2              = (const float*)d_in[12];
  const float* U3              = (const float*)d_in[13];
  const float* Wp1             = (const float*)d_in[14];
  const float* Wp2             = (const float*)d_in[15];
  const float* Wp3             = (const float*)d_in[16];
  const float* W_read          = (const float*)d_in[17];
  float* out = (float*)d_out;

  float* Abuf  = (float*)d_ws;                        // N*512 (A, then gA in place)
  float* xbuf  = Abuf  + (size_t)NNODES*KDIM*NSHD;    // N*32
  float* ybuf  = xbuf  + (size_t)NNODES*KDIM;         // N*32
  float* lut   = ybuf  + (size_t)NNODES*KDIM;         // 2050*64 = 131200
  unsigned short* S3frag = (unsigned short*)(lut + (size_t)2050*64); // 3584 -> 1792 fl, pad 1824
  int* gtab    = (int*)((float*)S3frag + 1824);       // 24 -> pad 32
  float* c123  = (float*)(gtab + 32);                 // 96 -> pad 128
  float* econ  = c123  + 128;                         // N
  float* e0con = econ  + NNODES;                      // N
  float4* vbuf4 = (float4*)(e0con + NNODES);          // E float4 (16B aligned)
  float* gvx   = (float*)(vbuf4 + (size_t)NEDGES);    // E
  float* gvy   = gvx + NEDGES;                        // E
  float* gvz   = gvy + NEDGES;                        // E
  int* sndbuf  = (int*)(gvz + NEDGES);                // E
  int* rcvbuf  = sndbuf + NEDGES;                     // E
  int* pos_of_e = rcvbuf + NEDGES;                    // E
  int* cnt       = pos_of_e + NEDGES;                 // N (cnt & cnt2 adjacent)
  int* cnt2      = cnt + NNODES;                      // N
  int* row_start = cnt2 + NNODES;                     // N+1 (pad 64)
  int* row2      = row_start + NNODES + 64;           // N+1 (pad 64)
  int* woff      = row2 + NNODES + 64;                // N
  int* woff2     = woff + NNODES;                     // N
  int* elist2    = woff2 + NNODES;                    // E

  hipMemsetAsync(out, 0, sizeof(float)*NGRAPH, stream);
  hipMemsetAsync(cnt, 0, sizeof(int)*2*NNODES, stream);

  prep_kernel<<<1,256,0,stream>>>(U2,U3,Wp1,Wp2,Wp3,W_read,S3frag,gtab,c123);
  lut_kernel<<<(LUTN+1+255)/256,256,0,stream>>>(W_r1,b_r1,W_r2,lut);
  count_kernel<<<NEDGES/256,256,0,stream>>>(edge_index, cnt, cnt2);
  scan2_kernel<<<2,1024,0,stream>>>(cnt, row_start, woff, cnt2, row2, woff2);
  scatter_geom_kernel<<<NEDGES/256,256,0,stream>>>(edge_index, shifts, positions,
                                                   woff, pos_of_e, vbuf4, sndbuf, rcvbuf);
  csr2_scatter_kernel<<<NEDGES/256,256,0,stream>>>(edge_index, pos_of_e, woff2, elist2);
  node_embed_kernel<<<NNODES/4,256,0,stream>>>(node_attrs,W_embed,W_up,atomic_energies,
                                               xbuf,ybuf,e0con);
  node_accA_kernel<<<NNODES/4,256,0,stream>>>(row_start,vbuf4,sndbuf,ybuf,lut,Abuf);
  node_b_kernel<<<NNODES/4,256,0,stream>>>(Abuf,xbuf,S3frag,gtab,c123,W_read,econ);
  reduce_e_kernel<<<NNODES/256,256,0,stream>>>(econ,e0con,batch,out);
  edge_bwd_kernel<<<NEDGES/256,256,0,stream>>>(sndbuf,rcvbuf,vbuf4,ybuf,lut,Abuf,
                                               gvx,gvy,gvz);
  force_kernel<<<NNODES/256,256,0,stream>>>(row_start,row2,elist2,gvx,gvy,gvz,out+NGRAPH);
}